// Round 1
// baseline (419.799 us; speedup 1.0000x reference)
//
#include <hip/hip_runtime.h>
#include <hip/hip_fp16.h>
#include <math.h>

#define B_ 4
#define T_ 1024
#define D_ 512
#define H_ 8
#define HD_ 64
#define KN 30
#define ED_ 128
#define DFF_ 2048
#define M_ 4096   // B*T
#define BH_ 32

typedef _Float16 f16;
typedef __attribute__((ext_vector_type(8))) _Float16 f16x8;
typedef __attribute__((ext_vector_type(4))) float f32x4;

#define MFMA16 __builtin_amdgcn_mfma_f32_16x16x32_f16

__device__ __forceinline__ f16x8 ld8(const f16* p){ return *reinterpret_cast<const f16x8*>(p); }

// ---------------- fp32 -> fp16 convert (vectorized) ----------------
__global__ __launch_bounds__(256) void cvt_kernel(const float* __restrict__ in,
                                                  f16* __restrict__ out, int n4){
  int i = blockIdx.x*256 + threadIdx.x;
  if (i >= n4) return;
  float4 v = reinterpret_cast<const float4*>(in)[i];
  union { f16 h[4]; ushort4 u; } o;
  o.h[0]=(f16)v.x; o.h[1]=(f16)v.y; o.h[2]=(f16)v.z; o.h[3]=(f16)v.w;
  reinterpret_cast<ushort4*>(out)[i] = o.u;
}

__global__ __launch_bounds__(256) void zero_kernel(float* __restrict__ p, int n){
  int i = blockIdx.x*256 + threadIdx.x;
  if (i < n) p[i] = 0.f;
}

// ---------------- generic MFMA GEMM: C = X @ W.T  (+bias, epilogues) --------
// X [M,Kd] f16 row-major, W [N,Kd] f16 row-major.
// EPI 0: f16 out = (acc+bias)*scale      (q/k projections)
// EPI 1: f16 out = gelu_exact(acc+bias)  (FF1)
// EPI 2: f32 out = acc+bias              (out-proj raw, FF2 raw)
// EPI 3: f16 transposed v-layout: vT[(b*H+h)*HD+dl][t]  (v projection)
template<int EPI>
__global__ __launch_bounds__(256) void gemm_xwt(
    const f16* __restrict__ X, const f16* __restrict__ W,
    const float* __restrict__ bias, void* __restrict__ outp,
    int M, int N, int Kd, int ldo, float scale)
{
  const int w    = threadIdx.x >> 6;
  const int lane = threadIdx.x & 63;
  const int l16  = lane & 15, l4 = lane >> 4;
  const int rb   = blockIdx.y*64 + w*16;
  const int cb   = blockIdx.x*64;
  const f16* xp = X + (size_t)(rb + l16)*Kd + l4*8;
  const f16* wp = W + (size_t)(cb + l16)*Kd + l4*8;
  f32x4 acc[4] = {(f32x4){0,0,0,0},(f32x4){0,0,0,0},(f32x4){0,0,0,0},(f32x4){0,0,0,0}};
  for (int k = 0; k < Kd; k += 32){
    f16x8 a = ld8(xp + k);
#pragma unroll
    for (int c = 0; c < 4; ++c){
      f16x8 b = ld8(wp + (size_t)c*16*Kd + k);
      acc[c] = MFMA16(a, b, acc[c], 0,0,0);
    }
  }
#pragma unroll
  for (int c = 0; c < 4; ++c){
    const int col = cb + c*16 + l16;
    const float bv = bias[col];
#pragma unroll
    for (int j = 0; j < 4; ++j){
      const int row = rb + l4*4 + j;
      float v = acc[c][j] + bv;
      if (EPI == 0){
        ((f16*)outp)[(size_t)row*ldo + col] = (f16)(v*scale);
      } else if (EPI == 1){
        v = 0.5f*v*(1.0f + erff(v*0.70710678118654752f));
        ((f16*)outp)[(size_t)row*ldo + col] = (f16)v;
      } else if (EPI == 2){
        ((float*)outp)[(size_t)row*ldo + col] = v;
      } else {
        const int b = row >> 10, t = row & (T_-1);
        const int h = col >> 6,  dl = col & (HD_-1);
        ((f16*)outp)[(((size_t)b*H_ + h)*HD_ + dl)*T_ + t] = (f16)v;
      }
    }
  }
}

// ---------------- fused QK^T + bias + mask + temp + softmax ----------------
// block = 16 q-rows of one (b,h). Writes normalized P (f16) and atomically
// accumulates edge-gather weights g[b,t,k] += p[b,h,t,E_idx]/H in fp32.
__global__ __launch_bounds__(256) void attn_score(
    const f16* __restrict__ q, const f16* __restrict__ k,
    const float* __restrict__ bias, const int* __restrict__ mask,
    const int* __restrict__ eidx, const float* __restrict__ tptr,
    f16* __restrict__ p, float* __restrict__ g)
{
  __shared__ float S[16][1024];     // exactly 64 KB
  const int blk = blockIdx.x;
  const int tb  = blk & 63;         // T/16 = 64 row-blocks
  const int bh  = blk >> 6;
  const int b   = bh >> 3, h = bh & 7;
  const int t0  = tb*16;
  const int w = threadIdx.x >> 6, lane = threadIdx.x & 63;
  const int l16 = lane & 15, l4 = lane >> 4;
  const float rtemp = exp2f(-2.0f*tanhf(tptr[0]));   // 1 / 4^tanh(t)

  const f16* qp = q + (size_t)(b*T_ + t0 + l16)*D_ + h*HD_ + l4*8;
  const f16x8 a0 = ld8(qp), a1 = ld8(qp + 32);
  for (int c = 0; c < 16; ++c){
    const int s0 = w*256 + c*16;
    const f16* kp = k + (size_t)(b*T_ + s0 + l16)*D_ + h*HD_ + l4*8;
    f32x4 acc = {0,0,0,0};
    acc = MFMA16(a0, ld8(kp),    acc, 0,0,0);
    acc = MFMA16(a1, ld8(kp+32), acc, 0,0,0);
    const int col = s0 + l16;
    const bool msk = (mask[b*T_ + col] == 0);
#pragma unroll
    for (int j = 0; j < 4; ++j){
      const int r = l4*4 + j;
      float v = acc[j] + bias[((size_t)(b*T_ + t0 + r))*T_ + col];
      if (msk) v = -1e9f;
      S[r][col] = v*rtemp;
    }
  }
  __syncthreads();

  // wave-parallel row softmax: 16 threads per row, shfl_xor within width-16
  const int row = threadIdx.x >> 4, sub = threadIdx.x & 15;
  float m = -3.4e38f;
#pragma unroll 8
  for (int i = 0; i < 64; ++i) m = fmaxf(m, S[row][sub + 16*i]);
  for (int o = 8; o; o >>= 1) m = fmaxf(m, __shfl_xor(m, o, 16));
  float l = 0.f;
#pragma unroll 8
  for (int i = 0; i < 64; ++i) l += __expf(S[row][sub + 16*i] - m);
  for (int o = 8; o; o >>= 1) l += __shfl_xor(l, o, 16);
  const float invl = 1.0f/l;
#pragma unroll 8
  for (int i = 0; i < 64; ++i) S[row][sub + 16*i] = __expf(S[row][sub + 16*i] - m)*invl;
  __syncthreads();

  // coalesced normalized-P write (f16, 16B per thread-store)
  const size_t pbase = ((size_t)bh*T_ + t0)*T_;
  for (int v8 = threadIdx.x; v8 < 16*1024/8; v8 += 256){
    const int r = v8 >> 7, c0 = (v8 & 127)*8;
    f16x8 t8;
#pragma unroll
    for (int i = 0; i < 8; ++i) t8[i] = (f16)S[r][c0+i];
    *reinterpret_cast<f16x8*>(p + pbase + (size_t)r*T_ + c0) = t8;
  }
  // edge gather contributions in fp32 (avoids f16 underflow on peaked rows)
  for (int jj = threadIdx.x; jj < 16*KN; jj += 256){
    const int r = jj / KN, kk = jj - r*KN;
    const int t = t0 + r;
    const int id = eidx[((size_t)(b*T_ + t))*KN + kk];
    atomicAdd(&g[((size_t)(b*T_ + t))*KN + kk], S[r][id]*0.125f);
  }
}

// ---------------- PV: attn = P @ V  (vT pre-transposed) --------------------
__global__ __launch_bounds__(256) void attn_pv(
    const f16* __restrict__ p, const f16* __restrict__ vT, f16* __restrict__ X2)
{
  const int bh = blockIdx.y, b = bh >> 3, h = bh & 7;
  const int w = threadIdx.x >> 6, lane = threadIdx.x & 63;
  const int l16 = lane & 15, l4 = lane >> 4;
  const int rt = blockIdx.x*64 + w*16;
  const f16* pp = p  + ((size_t)bh*T_ + rt + l16)*T_ + l4*8;
  const f16* vp = vT + ((size_t)bh*HD_ + l16)*T_ + l4*8;
  f32x4 acc[4] = {(f32x4){0,0,0,0},(f32x4){0,0,0,0},(f32x4){0,0,0,0},(f32x4){0,0,0,0}};
  for (int k = 0; k < T_; k += 32){
    f16x8 a = ld8(pp + k);
#pragma unroll
    for (int c = 0; c < 4; ++c)
      acc[c] = MFMA16(a, ld8(vp + (size_t)c*16*T_ + k), acc[c], 0,0,0);
  }
#pragma unroll
  for (int c = 0; c < 4; ++c){
    const int dl = c*16 + l16;
#pragma unroll
    for (int j = 0; j < 4; ++j){
      const int t = rt + l4*4 + j;
      X2[((size_t)(b*T_ + t))*640 + h*HD_ + dl] = (f16)acc[c][j];
    }
  }
}

// ---------------- edge: weighted neighbor-embedding mean -------------------
__global__ __launch_bounds__(128) void edge_kernel(
    const float* __restrict__ g, const float* __restrict__ E, f16* __restrict__ X2)
{
  __shared__ float gl[KN];
  __shared__ float ginv;
  const int bt = blockIdx.x;
  const int t = threadIdx.x;
  if (t < KN) gl[t] = g[(size_t)bt*KN + t];
  __syncthreads();
  if (t == 0){
    float s = 0.f;
#pragma unroll
    for (int i = 0; i < KN; ++i) s += gl[i];
    ginv = 1.0f/(s + 1e-6f);
  }
  __syncthreads();
  float acc = 0.f;
  const float* Ep = E + (size_t)bt*KN*ED_ + t;
#pragma unroll 5
  for (int kk = 0; kk < KN; ++kk) acc += gl[kk]*Ep[(size_t)kk*ED_];
  X2[(size_t)bt*640 + 512 + t] = (f16)(acc*ginv);
}

// ---------------- LayerNorm helpers ----------------------------------------
__device__ __forceinline__ float block_sum(float v, float* sbuf){
  for (int o = 32; o; o >>= 1) v += __shfl_down(v, o);
  __syncthreads();
  if ((threadIdx.x & 63) == 0) sbuf[threadIdx.x >> 6] = v;
  __syncthreads();
  return sbuf[0]+sbuf[1]+sbuf[2]+sbuf[3];
}

__global__ __launch_bounds__(256) void ln1_kernel(
    const float* __restrict__ hV, const float* __restrict__ hraw,
    const float* __restrict__ gn, const float* __restrict__ bn,
    float* __restrict__ hf, f16* __restrict__ hh)
{
  __shared__ float sbuf[4];
  const int r = blockIdx.x, t = threadIdx.x;
  const size_t base = (size_t)r*D_;
  float x0 = hV[base+t]     + hraw[base+t];
  float x1 = hV[base+t+256] + hraw[base+t+256];
  float s = block_sum(x0+x1, sbuf);
  const float mean = s*(1.f/512.f);
  float d0 = x0-mean, d1 = x1-mean;
  float vs = block_sum(d0*d0+d1*d1, sbuf);
  const float rstd = rsqrtf(vs*(1.f/512.f) + 1e-5f);
  float y0 = d0*rstd*gn[t]     + bn[t];
  float y1 = d1*rstd*gn[t+256] + bn[t+256];
  hf[base+t]     = y0;  hh[base+t]     = (f16)y0;
  hf[base+t+256] = y1;  hh[base+t+256] = (f16)y1;
}

__global__ __launch_bounds__(256) void final_kernel(
    const float* __restrict__ hf, const float* __restrict__ ffr,
    const float* __restrict__ gf, const float* __restrict__ bfv,
    const float* __restrict__ g2, const float* __restrict__ b2,
    float* __restrict__ out)
{
  __shared__ float sbuf[4];
  const int r = blockIdx.x, t = threadIdx.x;
  const size_t base = (size_t)r*D_;
  const float h0 = hf[base+t], h1 = hf[base+t+256];
  float x0 = h0 + ffr[base+t], x1 = h1 + ffr[base+t+256];
  float s = block_sum(x0+x1, sbuf);
  float mean = s*(1.f/512.f);
  float d0 = x0-mean, d1 = x1-mean;
  float vs = block_sum(d0*d0+d1*d1, sbuf);
  float rstd = rsqrtf(vs*(1.f/512.f) + 1e-6f);
  const float dh0 = d0*rstd*gf[t]     + bfv[t];
  const float dh1 = d1*rstd*gf[t+256] + bfv[t+256];
  const float y0 = h0 + dh0, y1 = h1 + dh1;
  s = block_sum(y0+y1, sbuf);
  mean = s*(1.f/512.f);
  d0 = y0-mean; d1 = y1-mean;
  vs = block_sum(d0*d0+d1*d1, sbuf);
  rstd = rsqrtf(vs*(1.f/512.f) + 1e-5f);
  out[base+t]     = d0*rstd*g2[t]     + b2[t];
  out[base+t+256] = d1*rstd*g2[t+256] + b2[t+256];
}

// ---------------------------------------------------------------------------
extern "C" void kernel_launch(void* const* d_in, const int* in_sizes, int n_in,
                              void* d_out, int out_size, void* d_ws, size_t ws_size,
                              hipStream_t stream)
{
  (void)in_sizes; (void)n_in; (void)out_size;
  const float* h_V  = (const float*)d_in[0];
  const float* kin  = (const float*)d_in[1];
  const float* vin  = (const float*)d_in[2];
  const float* E    = (const float*)d_in[3];
  const float* bias = (const float*)d_in[4];
  const float* Wq   = (const float*)d_in[5];
  const float* bq   = (const float*)d_in[6];
  const float* Wk   = (const float*)d_in[7];
  const float* bk   = (const float*)d_in[8];
  const float* Wv   = (const float*)d_in[9];
  const float* bv   = (const float*)d_in[10];
  const float* Wo   = (const float*)d_in[11];
  const float* bo   = (const float*)d_in[12];
  const float* tsc  = (const float*)d_in[13];
  const float* gn   = (const float*)d_in[14];
  const float* bn   = (const float*)d_in[15];
  const float* w1   = (const float*)d_in[16];
  const float* bw1  = (const float*)d_in[17];
  const float* w2   = (const float*)d_in[18];
  const float* bw2  = (const float*)d_in[19];
  const float* gf   = (const float*)d_in[20];
  const float* bfv  = (const float*)d_in[21];
  const float* g2   = (const float*)d_in[22];
  const float* b2   = (const float*)d_in[23];
  const int*   Eidx = (const int*)d_in[24];
  const int*   mask = (const int*)d_in[25];
  float* out = (float*)d_out;

  char* wsb = (char*)d_ws;
  size_t off = 0;
  auto alloc = [&](size_t bytes) -> void* {
    void* pp = wsb + off; off += (bytes + 255) & ~(size_t)255; return pp;
  };
  f16* hVb  = (f16*)alloc((size_t)M_*D_*2);
  f16* kbI  = (f16*)alloc((size_t)M_*D_*2);
  f16* vbI  = (f16*)alloc((size_t)M_*D_*2);
  f16* Wqb  = (f16*)alloc((size_t)D_*D_*2);
  f16* Wkb  = (f16*)alloc((size_t)D_*D_*2);
  f16* Wvb  = (f16*)alloc((size_t)D_*D_*2);
  f16* Wob  = (f16*)alloc((size_t)D_*(D_+ED_)*2);
  f16* w1b  = (f16*)alloc((size_t)DFF_*D_*2);
  f16* w2b  = (f16*)alloc((size_t)D_*DFF_*2);
  f16* qb   = (f16*)alloc((size_t)M_*D_*2);
  f16* kb   = (f16*)alloc((size_t)M_*D_*2);
  f16* vT   = (f16*)alloc((size_t)M_*D_*2);
  f16* Pm   = (f16*)alloc((size_t)BH_*T_*T_*2);
  f16* X2   = (f16*)alloc((size_t)M_*640*2);
  float* gbuf = (float*)alloc((size_t)M_*KN*4);
  float* hraw = (float*)alloc((size_t)M_*D_*4);   // reused as ffraw
  float* hf   = (float*)alloc((size_t)M_*D_*4);
  f16*   hh   = (f16*)alloc((size_t)M_*D_*2);
  f16*   ff1  = (f16*)alloc((size_t)M_*DFF_*2);
  if (ws_size < off) return;  // scratch insufficient -> loud validation failure
  float* ffraw = hraw;

  // 1) converts fp32 -> f16
  cvt_kernel<<<(M_*D_/4+255)/256,256,0,stream>>>(h_V, hVb, M_*D_/4);
  cvt_kernel<<<(M_*D_/4+255)/256,256,0,stream>>>(kin, kbI, M_*D_/4);
  cvt_kernel<<<(M_*D_/4+255)/256,256,0,stream>>>(vin, vbI, M_*D_/4);
  cvt_kernel<<<(D_*D_/4+255)/256,256,0,stream>>>(Wq, Wqb, D_*D_/4);
  cvt_kernel<<<(D_*D_/4+255)/256,256,0,stream>>>(Wk, Wkb, D_*D_/4);
  cvt_kernel<<<(D_*D_/4+255)/256,256,0,stream>>>(Wv, Wvb, D_*D_/4);
  cvt_kernel<<<(D_*(D_+ED_)/4+255)/256,256,0,stream>>>(Wo, Wob, D_*(D_+ED_)/4);
  cvt_kernel<<<(DFF_*D_/4+255)/256,256,0,stream>>>(w1, w1b, DFF_*D_/4);
  cvt_kernel<<<(D_*DFF_/4+255)/256,256,0,stream>>>(w2, w2b, D_*DFF_/4);
  zero_kernel<<<(M_*KN+255)/256,256,0,stream>>>(gbuf, M_*KN);

  // 2) projections (q scaled by HD^-0.5; v written pre-transposed)
  gemm_xwt<0><<<dim3(D_/64, M_/64),256,0,stream>>>(hVb, Wqb, bq, qb, M_, D_, D_, D_, 0.125f);
  gemm_xwt<0><<<dim3(D_/64, M_/64),256,0,stream>>>(kbI, Wkb, bk, kb, M_, D_, D_, D_, 1.0f);
  gemm_xwt<3><<<dim3(D_/64, M_/64),256,0,stream>>>(vbI, Wvb, bv, vT, M_, D_, D_, D_, 1.0f);

  // 3) attention scores + softmax + edge-gather accumulation
  attn_score<<<BH_*(T_/16),256,0,stream>>>(qb, kb, bias, mask, Eidx, tsc, Pm, gbuf);

  // 4) PV
  attn_pv<<<dim3(T_/64, BH_),256,0,stream>>>(Pm, vT, X2);

  // 5) edge embedding
  edge_kernel<<<M_,128,0,stream>>>(gbuf, E, X2);

  // 6) out-proj + residual LN
  gemm_xwt<2><<<dim3(D_/64, M_/64),256,0,stream>>>(X2, Wob, bo, hraw, M_, D_, D_+ED_, D_, 1.0f);
  ln1_kernel<<<M_,256,0,stream>>>(h_V, hraw, gn, bn, hf, hh);

  // 7) FFN
  gemm_xwt<1><<<dim3(DFF_/64, M_/64),256,0,stream>>>(hh, w1b, bw1, ff1, M_, DFF_, D_, DFF_, 1.0f);
  gemm_xwt<2><<<dim3(D_/64, M_/64),256,0,stream>>>(ff1, w2b, bw2, ffraw, M_, D_, DFF_, D_, 1.0f);

  // 8) final double-LN
  final_kernel<<<M_,256,0,stream>>>(hf, ffraw, gf, bfv, g2, b2, out);
}

// Round 2
// 246.264 us; speedup vs baseline: 1.7047x; 1.7047x over previous
//
#include <hip/hip_runtime.h>
#include <hip/hip_fp16.h>
#include <math.h>

#define B_ 4
#define T_ 1024
#define D_ 512
#define H_ 8
#define HD_ 64
#define KN 30
#define ED_ 128
#define DFF_ 2048
#define M_ 4096   // B*T
#define BH_ 32

typedef _Float16 f16;
typedef __attribute__((ext_vector_type(8))) _Float16 f16x8;
typedef __attribute__((ext_vector_type(4))) float f32x4;

#define MFMA16 __builtin_amdgcn_mfma_f32_16x16x32_f16

__device__ __forceinline__ f16x8 ld8(const f16* p){ return *reinterpret_cast<const f16x8*>(p); }

__device__ __forceinline__ void gld16(const void* g, void* l){
  __builtin_amdgcn_global_load_lds((const __attribute__((address_space(1))) void*)g,
                                   (__attribute__((address_space(3))) void*)l, 16, 0, 0);
}

// ---------------- fp32 -> fp16 convert (vectorized) ----------------
__global__ __launch_bounds__(256) void cvt_kernel(const float* __restrict__ in,
                                                  f16* __restrict__ out, int n4){
  int i = blockIdx.x*256 + threadIdx.x;
  if (i >= n4) return;
  float4 v = reinterpret_cast<const float4*>(in)[i];
  union { f16 h[4]; ushort4 u; } o;
  o.h[0]=(f16)v.x; o.h[1]=(f16)v.y; o.h[2]=(f16)v.z; o.h[3]=(f16)v.w;
  reinterpret_cast<ushort4*>(out)[i] = o.u;
}

__global__ __launch_bounds__(256) void zero_kernel(float* __restrict__ p, int n){
  int i = blockIdx.x*256 + threadIdx.x;
  if (i < n) p[i] = 0.f;
}

// =============== staged MFMA GEMM (m97 structure): C = X @ W.T ==============
// 128x128 tile, BK=32, 4 waves in 2x2, each wave 64x64 (4x4 16x16x32 frags).
// global_load_lds width-16 staging, linear LDS, 2 barriers per K-step.
// EPI 1: f16 out = gelu_exact(acc+bias)   (FF1)
// EPI 2: f32 out = acc+bias               (out-proj raw, FF2 raw)
template<int EPI>
__global__ __launch_bounds__(256,2) void gemm_tile(
    const f16* __restrict__ X, const f16* __restrict__ W,
    const float* __restrict__ bias, void* __restrict__ outp,
    int Kd, int ldo, int nbN)
{
  __shared__ f16 As[128*32];
  __shared__ f16 Bs[128*32];
  const int nwg = gridDim.x;                     // multiple of 8
  const int bid = blockIdx.x;
  const int swz = (bid & 7)*(nwg >> 3) + (bid >> 3);
  const int mb = swz / nbN, nb = swz - mb*nbN;
  const int rb = mb*128, cb = nb*128;
  const int tid = threadIdx.x;
  const int w = tid >> 6, lane = tid & 63;
  const int l16 = lane & 15, l4 = lane >> 4;
  const int wr = w >> 1, wc = w & 1;

  // staging map: wave w, call c stages rows [c*64+w*16, +16), lane l ->
  // row c*64+w*16+(l>>2), col (l&3)*8 elems; LDS linear => base + l*16B.
  const int sr = lane >> 2;
  const int sc = (lane & 3)*8;
  const f16* Ax0 = X + (size_t)(rb + w*16 + sr)*Kd + sc;
  const f16* Ax1 = X + (size_t)(rb + 64 + w*16 + sr)*Kd + sc;
  const f16* Bx0 = W + (size_t)(cb + w*16 + sr)*Kd + sc;
  const f16* Bx1 = W + (size_t)(cb + 64 + w*16 + sr)*Kd + sc;
  f16* Ad0 = &As[(w*16)*32];
  f16* Ad1 = &As[(64 + w*16)*32];
  f16* Bd0 = &Bs[(w*16)*32];
  f16* Bd1 = &Bs[(64 + w*16)*32];

  f32x4 acc[4][4];
#pragma unroll
  for (int m = 0; m < 4; ++m)
#pragma unroll
    for (int n = 0; n < 4; ++n) acc[m][n] = (f32x4){0.f,0.f,0.f,0.f};

  for (int k0 = 0; k0 < Kd; k0 += 32){
    gld16(Ax0 + k0, Ad0);
    gld16(Ax1 + k0, Ad1);
    gld16(Bx0 + k0, Bd0);
    gld16(Bx1 + k0, Bd1);
    __syncthreads();                 // vmcnt(0) drained by compiler
    f16x8 a[4], b[4];
#pragma unroll
    for (int m = 0; m < 4; ++m) a[m] = ld8(&As[(wr*64 + m*16 + l16)*32 + l4*8]);
#pragma unroll
    for (int n = 0; n < 4; ++n) b[n] = ld8(&Bs[(wc*64 + n*16 + l16)*32 + l4*8]);
#pragma unroll
    for (int m = 0; m < 4; ++m)
#pragma unroll
      for (int n = 0; n < 4; ++n)
        acc[m][n] = MFMA16(a[m], b[n], acc[m][n], 0,0,0);
    __syncthreads();                 // reads done before next stage
  }

#pragma unroll
  for (int n = 0; n < 4; ++n){
    const int col = cb + wc*64 + n*16 + l16;
    const float bv = bias[col];
#pragma unroll
    for (int m = 0; m < 4; ++m){
#pragma unroll
      for (int j = 0; j < 4; ++j){
        const int row = rb + wr*64 + m*16 + l4*4 + j;
        float v = acc[m][n][j] + bv;
        if (EPI == 1){
          v = 0.5f*v*(1.0f + erff(v*0.70710678118654752f));
          ((f16*)outp)[(size_t)row*ldo + col] = (f16)v;
        } else {
          ((float*)outp)[(size_t)row*ldo + col] = v;
        }
      }
    }
  }
}

// =============== batched QKV projection (one launch, 3 GEMMs) ===============
// grid = 384: gemm g in {q,k,v}, 128 blocks each (M=4096/128 x N=512/128).
// q: f16 out * 0.125 ; k: f16 out ; v: f16 transposed vT[(b*H+h)*HD+dl][t].
__global__ __launch_bounds__(256,2) void qkv_tile(
    const f16* __restrict__ hV, const f16* __restrict__ kI, const f16* __restrict__ vI,
    const f16* __restrict__ Wq, const f16* __restrict__ Wk, const f16* __restrict__ Wv,
    const float* __restrict__ bq, const float* __restrict__ bk, const float* __restrict__ bv,
    f16* __restrict__ qo, f16* __restrict__ ko, f16* __restrict__ vT)
{
  __shared__ f16 As[128*32];
  __shared__ f16 Bs[128*32];
  const int bid = blockIdx.x;
  const int swz = (bid & 7)*48 + (bid >> 3);
  const int g = swz >> 7;                  // /128
  const int r = swz & 127;
  const int mb = r >> 2, nb = r & 3;
  const f16* X  = (g == 0) ? hV : ((g == 1) ? kI : vI);
  const f16* W  = (g == 0) ? Wq : ((g == 1) ? Wk : Wv);
  const float* bias = (g == 0) ? bq : ((g == 1) ? bk : bv);
  const int rb = mb*128, cb = nb*128;
  const int tid = threadIdx.x;
  const int w = tid >> 6, lane = tid & 63;
  const int l16 = lane & 15, l4 = lane >> 4;
  const int wr = w >> 1, wc = w & 1;
  const int sr = lane >> 2, sc = (lane & 3)*8;
  const f16* Ax0 = X + (size_t)(rb + w*16 + sr)*D_ + sc;
  const f16* Ax1 = X + (size_t)(rb + 64 + w*16 + sr)*D_ + sc;
  const f16* Bx0 = W + (size_t)(cb + w*16 + sr)*D_ + sc;
  const f16* Bx1 = W + (size_t)(cb + 64 + w*16 + sr)*D_ + sc;
  f16* Ad0 = &As[(w*16)*32];
  f16* Ad1 = &As[(64 + w*16)*32];
  f16* Bd0 = &Bs[(w*16)*32];
  f16* Bd1 = &Bs[(64 + w*16)*32];

  f32x4 acc[4][4];
#pragma unroll
  for (int m = 0; m < 4; ++m)
#pragma unroll
    for (int n = 0; n < 4; ++n) acc[m][n] = (f32x4){0.f,0.f,0.f,0.f};

  for (int k0 = 0; k0 < D_; k0 += 32){
    gld16(Ax0 + k0, Ad0);
    gld16(Ax1 + k0, Ad1);
    gld16(Bx0 + k0, Bd0);
    gld16(Bx1 + k0, Bd1);
    __syncthreads();
    f16x8 a[4], b[4];
#pragma unroll
    for (int m = 0; m < 4; ++m) a[m] = ld8(&As[(wr*64 + m*16 + l16)*32 + l4*8]);
#pragma unroll
    for (int n = 0; n < 4; ++n) b[n] = ld8(&Bs[(wc*64 + n*16 + l16)*32 + l4*8]);
#pragma unroll
    for (int m = 0; m < 4; ++m)
#pragma unroll
      for (int n = 0; n < 4; ++n)
        acc[m][n] = MFMA16(a[m], b[n], acc[m][n], 0,0,0);
    __syncthreads();
  }

  const float scale = (g == 0) ? 0.125f : 1.0f;
  f16* out = (g == 0) ? qo : ko;
#pragma unroll
  for (int n = 0; n < 4; ++n){
    const int col = cb + wc*64 + n*16 + l16;
    const float bv = bias[col];
#pragma unroll
    for (int m = 0; m < 4; ++m){
#pragma unroll
      for (int j = 0; j < 4; ++j){
        const int row = rb + wr*64 + m*16 + l4*4 + j;
        const float v = (acc[m][n][j] + bv)*scale;
        if (g < 2){
          out[(size_t)row*D_ + col] = (f16)v;
        } else {
          const int b = row >> 10, t = row & (T_-1);
          const int h = col >> 6,  dl = col & (HD_-1);
          vT[(((size_t)b*H_ + h)*HD_ + dl)*T_ + t] = (f16)v;
        }
      }
    }
  }
}

// ---------------- fused QK^T + bias + mask + temp + softmax ----------------
__global__ __launch_bounds__(256) void attn_score(
    const f16* __restrict__ q, const f16* __restrict__ k,
    const float* __restrict__ bias, const int* __restrict__ mask,
    const int* __restrict__ eidx, const float* __restrict__ tptr,
    f16* __restrict__ p, float* __restrict__ g)
{
  __shared__ float S[16][1024];     // exactly 64 KB
  const int blk = blockIdx.x;
  const int tb  = blk & 63;
  const int bh  = blk >> 6;
  const int b   = bh >> 3, h = bh & 7;
  const int t0  = tb*16;
  const int w = threadIdx.x >> 6, lane = threadIdx.x & 63;
  const int l16 = lane & 15, l4 = lane >> 4;
  const float rtemp = exp2f(-2.0f*tanhf(tptr[0]));   // 1 / 4^tanh(t)

  const f16* qp = q + (size_t)(b*T_ + t0 + l16)*D_ + h*HD_ + l4*8;
  const f16x8 a0 = ld8(qp), a1 = ld8(qp + 32);
  for (int c = 0; c < 16; ++c){
    const int s0 = w*256 + c*16;
    const f16* kp = k + (size_t)(b*T_ + s0 + l16)*D_ + h*HD_ + l4*8;
    f32x4 acc = {0,0,0,0};
    acc = MFMA16(a0, ld8(kp),    acc, 0,0,0);
    acc = MFMA16(a1, ld8(kp+32), acc, 0,0,0);
    const int col = s0 + l16;
    const bool msk = (mask[b*T_ + col] == 0);
#pragma unroll
    for (int j = 0; j < 4; ++j){
      const int r = l4*4 + j;
      float v = acc[j] + bias[((size_t)(b*T_ + t0 + r))*T_ + col];
      if (msk) v = -1e9f;
      S[r][col] = v*rtemp;
    }
  }
  __syncthreads();

  const int row = threadIdx.x >> 4, sub = threadIdx.x & 15;
  float m = -3.4e38f;
#pragma unroll 8
  for (int i = 0; i < 64; ++i) m = fmaxf(m, S[row][sub + 16*i]);
  for (int o = 8; o; o >>= 1) m = fmaxf(m, __shfl_xor(m, o, 16));
  float l = 0.f;
#pragma unroll 8
  for (int i = 0; i < 64; ++i) l += __expf(S[row][sub + 16*i] - m);
  for (int o = 8; o; o >>= 1) l += __shfl_xor(l, o, 16);
  const float invl = 1.0f/l;
#pragma unroll 8
  for (int i = 0; i < 64; ++i) S[row][sub + 16*i] = __expf(S[row][sub + 16*i] - m)*invl;
  __syncthreads();

  const size_t pbase = ((size_t)bh*T_ + t0)*T_;
  for (int v8 = threadIdx.x; v8 < 16*1024/8; v8 += 256){
    const int r = v8 >> 7, c0 = (v8 & 127)*8;
    f16x8 t8;
#pragma unroll
    for (int i = 0; i < 8; ++i) t8[i] = (f16)S[r][c0+i];
    *reinterpret_cast<f16x8*>(p + pbase + (size_t)r*T_ + c0) = t8;
  }
  for (int jj = threadIdx.x; jj < 16*KN; jj += 256){
    const int r = jj / KN, kk = jj - r*KN;
    const int t = t0 + r;
    const int id = eidx[((size_t)(b*T_ + t))*KN + kk];
    atomicAdd(&g[((size_t)(b*T_ + t))*KN + kk], S[r][id]*0.125f);
  }
}

// =============== staged PV: attn = P @ V (vT pre-transposed) ===============
// tile 128(t) x 64(d), BK=64; 4 waves, each 32x64 (2x4 frags).
__global__ __launch_bounds__(256,2) void pv_tile(
    const f16* __restrict__ P, const f16* __restrict__ vT, f16* __restrict__ X2)
{
  __shared__ f16 Ps[128*64];
  __shared__ f16 Vs[64*64];
  const int bh = blockIdx.y, b = bh >> 3, h = bh & 7;
  const int rt = blockIdx.x*128;
  const int tid = threadIdx.x, w = tid >> 6, lane = tid & 63;
  const int l16 = lane & 15, l4 = lane >> 4;
  const int sr = lane >> 3, sc = (lane & 7)*8;   // 8 rows/call, 128B rows
  const f16* Pg = P + ((size_t)bh*T_ + rt)*T_;

  f32x4 acc[2][4];
#pragma unroll
  for (int m = 0; m < 2; ++m)
#pragma unroll
    for (int n = 0; n < 4; ++n) acc[m][n] = (f32x4){0.f,0.f,0.f,0.f};

  for (int k0 = 0; k0 < T_; k0 += 64){
#pragma unroll
    for (int c = 0; c < 4; ++c){
      const int row = w*32 + c*8 + sr;
      gld16(Pg + (size_t)row*T_ + k0 + sc, &Ps[(w*32 + c*8)*64]);
    }
#pragma unroll
    for (int c = 0; c < 2; ++c){
      const int row = w*16 + c*8 + sr;
      gld16(vT + ((size_t)bh*HD_ + row)*T_ + k0 + sc, &Vs[(w*16 + c*8)*64]);
    }
    __syncthreads();
#pragma unroll
    for (int kk = 0; kk < 2; ++kk){
      f16x8 a[2], bfr[4];
#pragma unroll
      for (int m = 0; m < 2; ++m) a[m] = ld8(&Ps[(w*32 + m*16 + l16)*64 + kk*32 + l4*8]);
#pragma unroll
      for (int n = 0; n < 4; ++n) bfr[n] = ld8(&Vs[(n*16 + l16)*64 + kk*32 + l4*8]);
#pragma unroll
      for (int m = 0; m < 2; ++m)
#pragma unroll
        for (int n = 0; n < 4; ++n)
          acc[m][n] = MFMA16(a[m], bfr[n], acc[m][n], 0,0,0);
    }
    __syncthreads();
  }

#pragma unroll
  for (int m = 0; m < 2; ++m)
#pragma unroll
    for (int n = 0; n < 4; ++n)
#pragma unroll
      for (int j = 0; j < 4; ++j){
        const int t = rt + w*32 + m*16 + l4*4 + j;
        const int dl = n*16 + l16;
        X2[((size_t)(b*T_ + t))*640 + h*HD_ + dl] = (f16)acc[m][n][j];
      }
}

// ---------------- edge: weighted neighbor-embedding mean -------------------
__global__ __launch_bounds__(128) void edge_kernel(
    const float* __restrict__ g, const float* __restrict__ E, f16* __restrict__ X2)
{
  __shared__ float gl[KN];
  __shared__ float ginv;
  const int bt = blockIdx.x;
  const int t = threadIdx.x;
  if (t < KN) gl[t] = g[(size_t)bt*KN + t];
  __syncthreads();
  if (t == 0){
    float s = 0.f;
#pragma unroll
    for (int i = 0; i < KN; ++i) s += gl[i];
    ginv = 1.0f/(s + 1e-6f);
  }
  __syncthreads();
  float acc = 0.f;
  const float* Ep = E + (size_t)bt*KN*ED_ + t;
#pragma unroll 5
  for (int kk = 0; kk < KN; ++kk) acc += gl[kk]*Ep[(size_t)kk*ED_];
  X2[(size_t)bt*640 + 512 + t] = (f16)(acc*ginv);
}

// ---------------- LayerNorm helpers ----------------------------------------
__device__ __forceinline__ float block_sum(float v, float* sbuf){
  for (int o = 32; o; o >>= 1) v += __shfl_down(v, o);
  __syncthreads();
  if ((threadIdx.x & 63) == 0) sbuf[threadIdx.x >> 6] = v;
  __syncthreads();
  return sbuf[0]+sbuf[1]+sbuf[2]+sbuf[3];
}

__global__ __launch_bounds__(256) void ln1_kernel(
    const float* __restrict__ hV, const float* __restrict__ hraw,
    const float* __restrict__ gn, const float* __restrict__ bn,
    float* __restrict__ hf, f16* __restrict__ hh)
{
  __shared__ float sbuf[4];
  const int r = blockIdx.x, t = threadIdx.x;
  const size_t base = (size_t)r*D_;
  float x0 = hV[base+t]     + hraw[base+t];
  float x1 = hV[base+t+256] + hraw[base+t+256];
  float s = block_sum(x0+x1, sbuf);
  const float mean = s*(1.f/512.f);
  float d0 = x0-mean, d1 = x1-mean;
  float vs = block_sum(d0*d0+d1*d1, sbuf);
  const float rstd = rsqrtf(vs*(1.f/512.f) + 1e-5f);
  float y0 = d0*rstd*gn[t]     + bn[t];
  float y1 = d1*rstd*gn[t+256] + bn[t+256];
  hf[base+t]     = y0;  hh[base+t]     = (f16)y0;
  hf[base+t+256] = y1;  hh[base+t+256] = (f16)y1;
}

__global__ __launch_bounds__(256) void final_kernel(
    const float* __restrict__ hf, const float* __restrict__ ffr,
    const float* __restrict__ gf, const float* __restrict__ bfv,
    const float* __restrict__ g2, const float* __restrict__ b2,
    float* __restrict__ out)
{
  __shared__ float sbuf[4];
  const int r = blockIdx.x, t = threadIdx.x;
  const size_t base = (size_t)r*D_;
  const float h0 = hf[base+t], h1 = hf[base+t+256];
  float x0 = h0 + ffr[base+t], x1 = h1 + ffr[base+t+256];
  float s = block_sum(x0+x1, sbuf);
  float mean = s*(1.f/512.f);
  float d0 = x0-mean, d1 = x1-mean;
  float vs = block_sum(d0*d0+d1*d1, sbuf);
  float rstd = rsqrtf(vs*(1.f/512.f) + 1e-6f);
  const float dh0 = d0*rstd*gf[t]     + bfv[t];
  const float dh1 = d1*rstd*gf[t+256] + bfv[t+256];
  const float y0 = h0 + dh0, y1 = h1 + dh1;
  s = block_sum(y0+y1, sbuf);
  mean = s*(1.f/512.f);
  d0 = y0-mean; d1 = y1-mean;
  vs = block_sum(d0*d0+d1*d1, sbuf);
  rstd = rsqrtf(vs*(1.f/512.f) + 1e-5f);
  out[base+t]     = d0*rstd*g2[t]     + b2[t];
  out[base+t+256] = d1*rstd*g2[t+256] + b2[t+256];
}

// ---------------------------------------------------------------------------
extern "C" void kernel_launch(void* const* d_in, const int* in_sizes, int n_in,
                              void* d_out, int out_size, void* d_ws, size_t ws_size,
                              hipStream_t stream)
{
  (void)in_sizes; (void)n_in; (void)out_size;
  const float* h_V  = (const float*)d_in[0];
  const float* kin  = (const float*)d_in[1];
  const float* vin  = (const float*)d_in[2];
  const float* E    = (const float*)d_in[3];
  const float* bias = (const float*)d_in[4];
  const float* Wq   = (const float*)d_in[5];
  const float* bq   = (const float*)d_in[6];
  const float* Wk   = (const float*)d_in[7];
  const float* bk   = (const float*)d_in[8];
  const float* Wv   = (const float*)d_in[9];
  const float* bv   = (const float*)d_in[10];
  const float* Wo   = (const float*)d_in[11];
  const float* bo   = (const float*)d_in[12];
  const float* tsc  = (const float*)d_in[13];
  const float* gn   = (const float*)d_in[14];
  const float* bn   = (const float*)d_in[15];
  const float* w1   = (const float*)d_in[16];
  const float* bw1  = (const float*)d_in[17];
  const float* w2   = (const float*)d_in[18];
  const float* bw2  = (const float*)d_in[19];
  const float* gf   = (const float*)d_in[20];
  const float* bfv  = (const float*)d_in[21];
  const float* g2   = (const float*)d_in[22];
  const float* b2   = (const float*)d_in[23];
  const int*   Eidx = (const int*)d_in[24];
  const int*   mask = (const int*)d_in[25];
  float* out = (float*)d_out;

  char* wsb = (char*)d_ws;
  size_t off = 0;
  auto alloc = [&](size_t bytes) -> void* {
    void* pp = wsb + off; off += (bytes + 255) & ~(size_t)255; return pp;
  };
  f16* hVb  = (f16*)alloc((size_t)M_*D_*2);
  f16* kbI  = (f16*)alloc((size_t)M_*D_*2);
  f16* vbI  = (f16*)alloc((size_t)M_*D_*2);
  f16* Wqb  = (f16*)alloc((size_t)D_*D_*2);
  f16* Wkb  = (f16*)alloc((size_t)D_*D_*2);
  f16* Wvb  = (f16*)alloc((size_t)D_*D_*2);
  f16* Wob  = (f16*)alloc((size_t)D_*(D_+ED_)*2);
  f16* w1b  = (f16*)alloc((size_t)DFF_*D_*2);
  f16* w2b  = (f16*)alloc((size_t)D_*DFF_*2);
  f16* qb   = (f16*)alloc((size_t)M_*D_*2);
  f16* kb   = (f16*)alloc((size_t)M_*D_*2);
  f16* vT   = (f16*)alloc((size_t)M_*D_*2);
  f16* Pm   = (f16*)alloc((size_t)BH_*T_*T_*2);
  f16* X2   = (f16*)alloc((size_t)M_*640*2);
  float* gbuf = (float*)alloc((size_t)M_*KN*4);
  float* hraw = (float*)alloc((size_t)M_*D_*4);   // reused as ffraw
  float* hf   = (float*)alloc((size_t)M_*D_*4);
  f16*   hh   = (f16*)alloc((size_t)M_*D_*2);
  f16*   ff1  = (f16*)alloc((size_t)M_*DFF_*2);
  if (ws_size < off) return;  // scratch insufficient -> loud validation failure
  float* ffraw = hraw;

  // 1) converts fp32 -> f16
  cvt_kernel<<<(M_*D_/4+255)/256,256,0,stream>>>(h_V, hVb, M_*D_/4);
  cvt_kernel<<<(M_*D_/4+255)/256,256,0,stream>>>(kin, kbI, M_*D_/4);
  cvt_kernel<<<(M_*D_/4+255)/256,256,0,stream>>>(vin, vbI, M_*D_/4);
  cvt_kernel<<<(D_*D_/4+255)/256,256,0,stream>>>(Wq, Wqb, D_*D_/4);
  cvt_kernel<<<(D_*D_/4+255)/256,256,0,stream>>>(Wk, Wkb, D_*D_/4);
  cvt_kernel<<<(D_*D_/4+255)/256,256,0,stream>>>(Wv, Wvb, D_*D_/4);
  cvt_kernel<<<(D_*(D_+ED_)/4+255)/256,256,0,stream>>>(Wo, Wob, D_*(D_+ED_)/4);
  cvt_kernel<<<(DFF_*D_/4+255)/256,256,0,stream>>>(w1, w1b, DFF_*D_/4);
  cvt_kernel<<<(D_*DFF_/4+255)/256,256,0,stream>>>(w2, w2b, D_*DFF_/4);
  zero_kernel<<<(M_*KN+255)/256,256,0,stream>>>(gbuf, M_*KN);

  // 2) batched q/k/v projections (q scaled; v written pre-transposed)
  qkv_tile<<<384,256,0,stream>>>(hVb, kbI, vbI, Wqb, Wkb, Wvb, bq, bk, bv, qb, kb, vT);

  // 3) attention scores + softmax + edge-gather accumulation
  attn_score<<<BH_*(T_/16),256,0,stream>>>(qb, kb, bias, mask, Eidx, tsc, Pm, gbuf);

  // 4) PV (staged)
  pv_tile<<<dim3(T_/128, BH_),256,0,stream>>>(Pm, vT, X2);

  // 5) edge embedding
  edge_kernel<<<M_,128,0,stream>>>(gbuf, E, X2);

  // 6) out-proj + residual LN
  gemm_tile<2><<<128,256,0,stream>>>(X2, Wob, bo, hraw, D_+ED_, D_, 4);
  ln1_kernel<<<M_,256,0,stream>>>(h_V, hraw, gn, bn, hf, hh);

  // 7) FFN
  gemm_tile<1><<<512,256,0,stream>>>(hh, w1b, bw1, ff1, D_, DFF_, 16);
  gemm_tile<2><<<128,256,0,stream>>>(ff1, w2b, bw2, ffraw, DFF_, D_, 4);

  // 8) final double-LN
  final_kernel<<<M_,256,0,stream>>>(hf, ffraw, gf, bfv, g2, b2, out);
}

// Round 6
// 216.049 us; speedup vs baseline: 1.9431x; 1.1398x over previous
//
#include <hip/hip_runtime.h>
#include <hip/hip_fp16.h>
#include <math.h>

#define B_ 4
#define T_ 1024
#define D_ 512
#define H_ 8
#define HD_ 64
#define KN 30
#define ED_ 128
#define DFF_ 2048
#define M_ 4096   // B*T
#define BH_ 32

typedef _Float16 f16;
typedef __attribute__((ext_vector_type(8))) _Float16 f16x8;
typedef __attribute__((ext_vector_type(4))) _Float16 f16x4;
typedef __attribute__((ext_vector_type(4))) float f32x4;

#define MFMA16 __builtin_amdgcn_mfma_f32_16x16x32_f16
#define LOG2E 1.44269504088896f

__device__ __forceinline__ f16x8 ld8(const f16* p){ return *reinterpret_cast<const f16x8*>(p); }

__device__ __forceinline__ void gld16(const void* g, void* l){
  __builtin_amdgcn_global_load_lds((const __attribute__((address_space(1))) void*)g,
                                   (__attribute__((address_space(3))) void*)l, 16, 0, 0);
}

// ---------------- combined fp32 -> fp16 convert (9 tensors, 1 launch) -------
struct CvtJobs {
  const float* s[9];
  f16* d[9];
  int start[10];   // cumulative block starts; each block = 256 float4s
};

__global__ __launch_bounds__(256) void cvt9_kernel(CvtJobs J){
  const int blk = blockIdx.x;
  int j = 0;
  while (j < 8 && blk >= J.start[j+1]) ++j;
  const int i = (blk - J.start[j])*256 + threadIdx.x;
  float4 v = reinterpret_cast<const float4*>(J.s[j])[i];
  union { f16 h[4]; ushort4 u; } o;
  o.h[0]=(f16)v.x; o.h[1]=(f16)v.y; o.h[2]=(f16)v.z; o.h[3]=(f16)v.w;
  reinterpret_cast<ushort4*>(J.d[j])[i] = o.u;
}

__global__ __launch_bounds__(256) void zero_kernel(float* __restrict__ p, int n){
  int i = blockIdx.x*256 + threadIdx.x;
  if (i < n) p[i] = 0.f;
}

// ---------------- bias prep: f16((bias + mask*-6e4) * rtemp * log2e) --------
__global__ __launch_bounds__(256) void biasprep_kernel(
    const float* __restrict__ bias, const int* __restrict__ mask,
    const float* __restrict__ tsc, f16* __restrict__ biasP)
{
  const int gid = blockIdx.x*256 + threadIdx.x;      // 524288 threads, 8 elems each
  const float s = exp2f(-2.0f*tanhf(tsc[0]))*LOG2E;  // log2e / 4^tanh(t)
  const int b = gid >> 17;                            // T*T/8 = 131072 per batch
  const int rem = gid & 131071;
  const int idx8 = rem*8;
  const int s0 = idx8 & 1023;
  const size_t gbase = (size_t)b*T_*T_ + idx8;
  float4 v0 = *reinterpret_cast<const float4*>(bias + gbase);
  float4 v1 = *reinterpret_cast<const float4*>(bias + gbase + 4);
  int4 m0 = *reinterpret_cast<const int4*>(mask + b*T_ + s0);
  int4 m1 = *reinterpret_cast<const int4*>(mask + b*T_ + s0 + 4);
  float x[8] = {v0.x,v0.y,v0.z,v0.w,v1.x,v1.y,v1.z,v1.w};
  int  mm[8] = {m0.x,m0.y,m0.z,m0.w,m1.x,m1.y,m1.z,m1.w};
  union { f16 h[8]; ushort4 u[2]; } o;
#pragma unroll
  for (int i = 0; i < 8; ++i){
    float t = (x[i] + (mm[i] ? 0.f : -60000.f))*s;
    o.h[i] = (f16)fmaxf(t, -60000.f);
  }
  reinterpret_cast<ushort4*>(biasP + gbase)[0] = o.u[0];
  reinterpret_cast<ushort4*>(biasP + gbase)[1] = o.u[1];
}

// =============== staged MFMA GEMM (m97 structure): C = X @ W.T ==============
template<int EPI>
__global__ __launch_bounds__(256,2) void gemm_tile(
    const f16* __restrict__ X, const f16* __restrict__ W,
    const float* __restrict__ bias, void* __restrict__ outp,
    int Kd, int ldo, int nbN)
{
  __shared__ f16 As[128*32];
  __shared__ f16 Bs[128*32];
  const int nwg = gridDim.x;
  const int bid = blockIdx.x;
  const int swz = (bid & 7)*(nwg >> 3) + (bid >> 3);
  const int mb = swz / nbN, nb = swz - mb*nbN;
  const int rb = mb*128, cb = nb*128;
  const int tid = threadIdx.x;
  const int w = tid >> 6, lane = tid & 63;
  const int l16 = lane & 15, l4 = lane >> 4;
  const int wr = w >> 1, wc = w & 1;
  const int sr = lane >> 2, sc = (lane & 3)*8;
  const f16* Ax0 = X + (size_t)(rb + w*16 + sr)*Kd + sc;
  const f16* Ax1 = X + (size_t)(rb + 64 + w*16 + sr)*Kd + sc;
  const f16* Bx0 = W + (size_t)(cb + w*16 + sr)*Kd + sc;
  const f16* Bx1 = W + (size_t)(cb + 64 + w*16 + sr)*Kd + sc;
  f16* Ad0 = &As[(w*16)*32];
  f16* Ad1 = &As[(64 + w*16)*32];
  f16* Bd0 = &Bs[(w*16)*32];
  f16* Bd1 = &Bs[(64 + w*16)*32];

  f32x4 acc[4][4];
#pragma unroll
  for (int m = 0; m < 4; ++m)
#pragma unroll
    for (int n = 0; n < 4; ++n) acc[m][n] = (f32x4){0.f,0.f,0.f,0.f};

  for (int k0 = 0; k0 < Kd; k0 += 32){
    gld16(Ax0 + k0, Ad0);
    gld16(Ax1 + k0, Ad1);
    gld16(Bx0 + k0, Bd0);
    gld16(Bx1 + k0, Bd1);
    __syncthreads();
    f16x8 a[4], b[4];
#pragma unroll
    for (int m = 0; m < 4; ++m) a[m] = ld8(&As[(wr*64 + m*16 + l16)*32 + l4*8]);
#pragma unroll
    for (int n = 0; n < 4; ++n) b[n] = ld8(&Bs[(wc*64 + n*16 + l16)*32 + l4*8]);
#pragma unroll
    for (int m = 0; m < 4; ++m)
#pragma unroll
      for (int n = 0; n < 4; ++n)
        acc[m][n] = MFMA16(a[m], b[n], acc[m][n], 0,0,0);
    __syncthreads();
  }

#pragma unroll
  for (int n = 0; n < 4; ++n){
    const int col = cb + wc*64 + n*16 + l16;
    const float bv = bias[col];
#pragma unroll
    for (int m = 0; m < 4; ++m){
#pragma unroll
      for (int j = 0; j < 4; ++j){
        const int row = rb + wr*64 + m*16 + l4*4 + j;
        float v = acc[m][n][j] + bv;
        if (EPI == 1){
          v = 0.5f*v*(1.0f + erff(v*0.70710678118654752f));
          ((f16*)outp)[(size_t)row*ldo + col] = (f16)v;
        } else {
          ((float*)outp)[(size_t)row*ldo + col] = v;
        }
      }
    }
  }
}

// =============== batched QKV projection (one launch, 3 GEMMs) ===============
// q epilogue folds 0.125 * rtemp * log2e (exp2-space softmax prescale).
__global__ __launch_bounds__(256,2) void qkv_tile(
    const f16* __restrict__ hV, const f16* __restrict__ kI, const f16* __restrict__ vI,
    const f16* __restrict__ Wq, const f16* __restrict__ Wk, const f16* __restrict__ Wv,
    const float* __restrict__ bq, const float* __restrict__ bk, const float* __restrict__ bv,
    const float* __restrict__ tsc,
    f16* __restrict__ qo, f16* __restrict__ ko, f16* __restrict__ vT)
{
  __shared__ f16 As[128*32];
  __shared__ f16 Bs[128*32];
  const int bid = blockIdx.x;
  const int swz = (bid & 7)*48 + (bid >> 3);
  const int g = swz >> 7;
  const int r = swz & 127;
  const int mb = r >> 2, nb = r & 3;
  const f16* X  = (g == 0) ? hV : ((g == 1) ? kI : vI);
  const f16* W  = (g == 0) ? Wq : ((g == 1) ? Wk : Wv);
  const float* bias = (g == 0) ? bq : ((g == 1) ? bk : bv);
  const int rb = mb*128, cb = nb*128;
  const int tid = threadIdx.x;
  const int w = tid >> 6, lane = tid & 63;
  const int l16 = lane & 15, l4 = lane >> 4;
  const int wr = w >> 1, wc = w & 1;
  const int sr = lane >> 2, sc = (lane & 3)*8;
  const f16* Ax0 = X + (size_t)(rb + w*16 + sr)*D_ + sc;
  const f16* Ax1 = X + (size_t)(rb + 64 + w*16 + sr)*D_ + sc;
  const f16* Bx0 = W + (size_t)(cb + w*16 + sr)*D_ + sc;
  const f16* Bx1 = W + (size_t)(cb + 64 + w*16 + sr)*D_ + sc;
  f16* Ad0 = &As[(w*16)*32];
  f16* Ad1 = &As[(64 + w*16)*32];
  f16* Bd0 = &Bs[(w*16)*32];
  f16* Bd1 = &Bs[(64 + w*16)*32];

  f32x4 acc[4][4];
#pragma unroll
  for (int m = 0; m < 4; ++m)
#pragma unroll
    for (int n = 0; n < 4; ++n) acc[m][n] = (f32x4){0.f,0.f,0.f,0.f};

  for (int k0 = 0; k0 < D_; k0 += 32){
    gld16(Ax0 + k0, Ad0);
    gld16(Ax1 + k0, Ad1);
    gld16(Bx0 + k0, Bd0);
    gld16(Bx1 + k0, Bd1);
    __syncthreads();
    f16x8 a[4], b[4];
#pragma unroll
    for (int m = 0; m < 4; ++m) a[m] = ld8(&As[(wr*64 + m*16 + l16)*32 + l4*8]);
#pragma unroll
    for (int n = 0; n < 4; ++n) b[n] = ld8(&Bs[(wc*64 + n*16 + l16)*32 + l4*8]);
#pragma unroll
    for (int m = 0; m < 4; ++m)
#pragma unroll
      for (int n = 0; n < 4; ++n)
        acc[m][n] = MFMA16(a[m], b[n], acc[m][n], 0,0,0);
    __syncthreads();
  }

  const float qs = exp2f(-2.0f*tanhf(tsc[0]))*LOG2E*0.125f;
  const float scale = (g == 0) ? qs : 1.0f;
  f16* out = (g == 0) ? qo : ko;
#pragma unroll
  for (int n = 0; n < 4; ++n){
    const int col = cb + wc*64 + n*16 + l16;
    const float bv = bias[col];
#pragma unroll
    for (int m = 0; m < 4; ++m){
#pragma unroll
      for (int j = 0; j < 4; ++j){
        const int row = rb + wr*64 + m*16 + l4*4 + j;
        const float v = (acc[m][n][j] + bv)*scale;
        if (g < 2){
          out[(size_t)row*D_ + col] = (f16)v;
        } else {
          const int b = row >> 10, t = row & (T_-1);
          const int h = col >> 6,  dl = col & (HD_-1);
          vT[(((size_t)b*H_ + h)*HD_ + dl)*T_ + t] = (f16)v;
        }
      }
    }
  }
}

// =============== fused attention: QK^T(swapped) + softmax + PV + gather =====
// block = 16 q-rows x one (b,h); 4 waves; wave w owns s-range [w*256,+256)
// for QK and d-cols [w*16,+16) for PV. Scores live in registers; P staged
// unnormalized f16 in LDS (stride 1032 = 16B-aligned, ~2-way banked);
// 1/l applied in PV epilogue and gather.
#define PSTR 1032
__global__ __launch_bounds__(256,4) void attn_fused(
    const f16* __restrict__ q, const f16* __restrict__ k, const f16* __restrict__ vT,
    const f16* __restrict__ biasP, const int* __restrict__ eidx,
    f16* __restrict__ X2, float* __restrict__ gout)
{
  __shared__ f16 Pb[16*PSTR];
  __shared__ float red[2][4][16];
  const int bid = blockIdx.x;
  const int swz = (bid & 7)*256 + (bid >> 3);   // XCD gets 4 contiguous bh
  const int bh = swz >> 6, tb = swz & 63;
  const int bi = bh >> 3, h = bh & 7;
  const int t0 = tb*16;
  const int tid = threadIdx.x, w = tid >> 6, lane = tid & 63;
  const int l16 = lane & 15, l4 = lane >> 4;

  // ---- stage bias tile [16][1024] f16 -> Pb (coalesced) ----
  {
    const f16* bsrc = biasP + ((size_t)(bi*T_ + t0))*T_;
#pragma unroll
    for (int p = 0; p < 8; ++p){
      const int idx = p*256 + tid;
      const int row = idx >> 7, col8 = (idx & 127)*8;
      f16x8 v = ld8(bsrc + row*T_ + col8);
      *reinterpret_cast<f16x8*>(&Pb[row*PSTR + col8]) = v;
    }
  }
  __syncthreads();

  // ---- QK^T swapped: acc[c][j] = S[s = sbase+c*16+l4*4+j][q = l16] ----
  const f16* qp = q + (size_t)(bi*T_ + t0 + l16)*D_ + h*HD_ + l4*8;
  const f16x8 q0 = ld8(qp), q1 = ld8(qp + 32);
  const int sbase = w*256;
  f32x4 acc[16];
#pragma unroll
  for (int c = 0; c < 16; ++c){
    const f16* kp = k + (size_t)(bi*T_ + sbase + c*16 + l16)*D_ + h*HD_ + l4*8;
    f32x4 a = {0.f,0.f,0.f,0.f};
    a = MFMA16(ld8(kp),      q0, a, 0,0,0);
    a = MFMA16(ld8(kp + 32), q1, a, 0,0,0);
    const f16x4 bfrg = *reinterpret_cast<const f16x4*>(&Pb[l16*PSTR + sbase + c*16 + l4*4]);
#pragma unroll
    for (int j = 0; j < 4; ++j) a[j] += (float)bfrg[j];
    acc[c] = a;
  }

  // ---- row max: in-lane (64 vals, one q-row per lane) + shfl + cross-wave --
  float m = -3.4e38f;
#pragma unroll
  for (int c = 0; c < 16; ++c)
#pragma unroll
    for (int j = 0; j < 4; ++j) m = fmaxf(m, acc[c][j]);
  m = fmaxf(m, __shfl_xor(m, 16));
  m = fmaxf(m, __shfl_xor(m, 32));
  if (lane < 16) red[0][w][lane] = m;
  __syncthreads();
  m = fmaxf(fmaxf(red[0][0][l16], red[0][1][l16]),
            fmaxf(red[0][2][l16], red[0][3][l16]));

  // ---- exp2, accumulate l, pack unnormalized P to LDS ----
  float l = 0.f;
#pragma unroll
  for (int c = 0; c < 16; ++c){
    f16x4 pp;
#pragma unroll
    for (int j = 0; j < 4; ++j){
      const float e = exp2f(acc[c][j] - m);
      l += e;
      pp[j] = (f16)e;
    }
    *reinterpret_cast<f16x4*>(&Pb[l16*PSTR + sbase + c*16 + l4*4]) = pp;
  }
  l += __shfl_xor(l, 16);
  l += __shfl_xor(l, 32);
  if (lane < 16) red[1][w][lane] = l;
  __syncthreads();   // P writes + partial sums all visible

  // ---- PV: wave w -> d-cols [w*16,+16); A = P from LDS, B = vT global ----
  f32x4 o = {0.f,0.f,0.f,0.f};
  const f16* vp = vT + ((size_t)bh*HD_ + w*16 + l16)*T_ + l4*8;
#pragma unroll
  for (int s0 = 0; s0 < T_; s0 += 32){
    f16x8 a = *reinterpret_cast<const f16x8*>(&Pb[l16*PSTR + s0 + l4*8]);
    f16x8 vfrg = ld8(vp + s0);
    o = MFMA16(a, vfrg, o, 0,0,0);
  }
#pragma unroll
  for (int j = 0; j < 4; ++j){
    const int row = l4*4 + j;
    const float lr = red[1][0][row] + red[1][1][row] + red[1][2][row] + red[1][3][row];
    const int t = t0 + row;
    X2[((size_t)(bi*T_ + t))*640 + h*HD_ + w*16 + l16] = (f16)(o[j]/lr);
  }

  // ---- edge gather: g[b,t,kk] += p_norm / H  (480 items > 256 threads:
  //      MUST be a strided loop, not a single predicated pass) ----
  for (int jj = tid; jj < 16*KN; jj += 256){
    const int r = jj/KN, kk = jj - r*KN;
    const float lr = red[1][0][r] + red[1][1][r] + red[1][2][r] + red[1][3][r];
    const int t = t0 + r;
    const int id = eidx[((size_t)(bi*T_ + t))*KN + kk];
    const float pv = (float)Pb[r*PSTR + id];
    atomicAdd(&gout[((size_t)(bi*T_ + t))*KN + kk], pv/lr*0.125f);
  }
}

// ---------------- edge: weighted neighbor-embedding mean -------------------
__global__ __launch_bounds__(128) void edge_kernel(
    const float* __restrict__ g, const float* __restrict__ E, f16* __restrict__ X2)
{
  __shared__ float gl[KN];
  __shared__ float ginv;
  const int bt = blockIdx.x;
  const int t = threadIdx.x;
  if (t < KN) gl[t] = g[(size_t)bt*KN + t];
  __syncthreads();
  if (t == 0){
    float s = 0.f;
#pragma unroll
    for (int i = 0; i < KN; ++i) s += gl[i];
    ginv = 1.0f/(s + 1e-6f);
  }
  __syncthreads();
  float acc = 0.f;
  const float* Ep = E + (size_t)bt*KN*ED_ + t;
#pragma unroll 5
  for (int kk = 0; kk < KN; ++kk) acc += gl[kk]*Ep[(size_t)kk*ED_];
  X2[(size_t)bt*640 + 512 + t] = (f16)(acc*ginv);
}

// ---------------- LayerNorm helpers ----------------------------------------
__device__ __forceinline__ float block_sum(float v, float* sbuf){
  for (int o = 32; o; o >>= 1) v += __shfl_down(v, o);
  __syncthreads();
  if ((threadIdx.x & 63) == 0) sbuf[threadIdx.x >> 6] = v;
  __syncthreads();
  return sbuf[0]+sbuf[1]+sbuf[2]+sbuf[3];
}

__global__ __launch_bounds__(256) void ln1_kernel(
    const float* __restrict__ hV, const float* __restrict__ hraw,
    const float* __restrict__ gn, const float* __restrict__ bn,
    float* __restrict__ hf, f16* __restrict__ hh)
{
  __shared__ float sbuf[4];
  const int r = blockIdx.x, t = threadIdx.x;
  const size_t base = (size_t)r*D_;
  float x0 = hV[base+t]     + hraw[base+t];
  float x1 = hV[base+t+256] + hraw[base+t+256];
  float s = block_sum(x0+x1, sbuf);
  const float mean = s*(1.f/512.f);
  float d0 = x0-mean, d1 = x1-mean;
  float vs = block_sum(d0*d0+d1*d1, sbuf);
  const float rstd = rsqrtf(vs*(1.f/512.f) + 1e-5f);
  float y0 = d0*rstd*gn[t]     + bn[t];
  float y1 = d1*rstd*gn[t+256] + bn[t+256];
  hf[base+t]     = y0;  hh[base+t]     = (f16)y0;
  hf[base+t+256] = y1;  hh[base+t+256] = (f16)y1;
}

__global__ __launch_bounds__(256) void final_kernel(
    const float* __restrict__ hf, const float* __restrict__ ffr,
    const float* __restrict__ gf, const float* __restrict__ bfv,
    const float* __restrict__ g2, const float* __restrict__ b2,
    float* __restrict__ out)
{
  __shared__ float sbuf[4];
  const int r = blockIdx.x, t = threadIdx.x;
  const size_t base = (size_t)r*D_;
  const float h0 = hf[base+t], h1 = hf[base+t+256];
  float x0 = h0 + ffr[base+t], x1 = h1 + ffr[base+t+256];
  float s = block_sum(x0+x1, sbuf);
  float mean = s*(1.f/512.f);
  float d0 = x0-mean, d1 = x1-mean;
  float vs = block_sum(d0*d0+d1*d1, sbuf);
  float rstd = rsqrtf(vs*(1.f/512.f) + 1e-6f);
  const float dh0 = d0*rstd*gf[t]     + bfv[t];
  const float dh1 = d1*rstd*gf[t+256] + bfv[t+256];
  const float y0 = h0 + dh0, y1 = h1 + dh1;
  s = block_sum(y0+y1, sbuf);
  mean = s*(1.f/512.f);
  d0 = y0-mean; d1 = y1-mean;
  vs = block_sum(d0*d0+d1*d1, sbuf);
  rstd = rsqrtf(vs*(1.f/512.f) + 1e-5f);
  out[base+t]     = d0*rstd*g2[t]     + b2[t];
  out[base+t+256] = d1*rstd*g2[t+256] + b2[t+256];
}

// ---------------------------------------------------------------------------
extern "C" void kernel_launch(void* const* d_in, const int* in_sizes, int n_in,
                              void* d_out, int out_size, void* d_ws, size_t ws_size,
                              hipStream_t stream)
{
  (void)in_sizes; (void)n_in; (void)out_size;
  const float* h_V  = (const float*)d_in[0];
  const float* kin  = (const float*)d_in[1];
  const float* vin  = (const float*)d_in[2];
  const float* E    = (const float*)d_in[3];
  const float* bias = (const float*)d_in[4];
  const float* Wq   = (const float*)d_in[5];
  const float* bq   = (const float*)d_in[6];
  const float* Wk   = (const float*)d_in[7];
  const float* bk   = (const float*)d_in[8];
  const float* Wv   = (const float*)d_in[9];
  const float* bv   = (const float*)d_in[10];
  const float* Wo   = (const float*)d_in[11];
  const float* bo   = (const float*)d_in[12];
  const float* tsc  = (const float*)d_in[13];
  const float* gn   = (const float*)d_in[14];
  const float* bn   = (const float*)d_in[15];
  const float* w1   = (const float*)d_in[16];
  const float* bw1  = (const float*)d_in[17];
  const float* w2   = (const float*)d_in[18];
  const float* bw2  = (const float*)d_in[19];
  const float* gf   = (const float*)d_in[20];
  const float* bfv  = (const float*)d_in[21];
  const float* g2   = (const float*)d_in[22];
  const float* b2   = (const float*)d_in[23];
  const int*   Eidx = (const int*)d_in[24];
  const int*   mask = (const int*)d_in[25];
  float* out = (float*)d_out;

  char* wsb = (char*)d_ws;
  size_t off = 0;
  auto alloc = [&](size_t bytes) -> void* {
    void* pp = wsb + off; off += (bytes + 255) & ~(size_t)255; return pp;
  };
  f16* hVb  = (f16*)alloc((size_t)M_*D_*2);
  f16* kbI  = (f16*)alloc((size_t)M_*D_*2);
  f16* vbI  = (f16*)alloc((size_t)M_*D_*2);
  f16* Wqb  = (f16*)alloc((size_t)D_*D_*2);
  f16* Wkb  = (f16*)alloc((size_t)D_*D_*2);
  f16* Wvb  = (f16*)alloc((size_t)D_*D_*2);
  f16* Wob  = (f16*)alloc((size_t)D_*(D_+ED_)*2);
  f16* w1b  = (f16*)alloc((size_t)DFF_*D_*2);
  f16* w2b  = (f16*)alloc((size_t)D_*DFF_*2);
  f16* qb   = (f16*)alloc((size_t)M_*D_*2);
  f16* kb   = (f16*)alloc((size_t)M_*D_*2);
  f16* vT   = (f16*)alloc((size_t)M_*D_*2);
  f16* biasP= (f16*)alloc((size_t)B_*T_*T_*2);
  f16* X2   = (f16*)alloc((size_t)M_*640*2);
  float* gbuf = (float*)alloc((size_t)M_*KN*4);
  float* hraw = (float*)alloc((size_t)M_*D_*4);   // reused as ffraw
  float* hf   = (float*)alloc((size_t)M_*D_*4);
  f16*   hh   = (f16*)alloc((size_t)M_*D_*2);
  f16*   ff1  = (f16*)alloc((size_t)M_*DFF_*2);
  if (ws_size < off) return;  // scratch insufficient -> loud validation failure
  float* ffraw = hraw;

  // 1) converts fp32 -> f16 (one launch) + bias prep + g zero
  {
    CvtJobs J;
    const float* srcs[9] = {h_V, kin, vin, Wq, Wk, Wv, Wo, w1, w2};
    f16* dsts[9] = {hVb, kbI, vbI, Wqb, Wkb, Wvb, Wob, w1b, w2b};
    const int n4s[9] = {M_*D_/4, M_*D_/4, M_*D_/4, D_*D_/4, D_*D_/4, D_*D_/4,
                        D_*(D_+ED_)/4, DFF_*D_/4, D_*DFF_/4};
    int cum = 0;
    for (int i = 0; i < 9; ++i){
      J.s[i] = srcs[i]; J.d[i] = dsts[i]; J.start[i] = cum;
      cum += n4s[i]/256;
    }
    J.start[9] = cum;
    cvt9_kernel<<<cum,256,0,stream>>>(J);
  }
  biasprep_kernel<<<B_*T_*T_/8/256,256,0,stream>>>(bias, mask, tsc, biasP);
  zero_kernel<<<(M_*KN+255)/256,256,0,stream>>>(gbuf, M_*KN);

  // 2) batched q/k/v projections (q pre-scaled for exp2 softmax; v -> vT)
  qkv_tile<<<384,256,0,stream>>>(hVb, kbI, vbI, Wqb, Wkb, Wvb, bq, bk, bv, tsc, qb, kb, vT);

  // 3) fused attention (QK^T + softmax + PV + edge gather)
  attn_fused<<<2048,256,0,stream>>>(qb, kb, vT, biasP, Eidx, X2, gbuf);

  // 4) edge embedding
  edge_kernel<<<M_,128,0,stream>>>(gbuf, E, X2);

  // 5) out-proj + residual LN
  gemm_tile<2><<<128,256,0,stream>>>(X2, Wob, bo, hraw, D_+ED_, D_, 4);
  ln1_kernel<<<M_,256,0,stream>>>(h_V, hraw, gn, bn, hf, hh);

  // 6) FFN
  gemm_tile<1><<<512,256,0,stream>>>(hh, w1b, bw1, ff1, D_, DFF_, 16);
  gemm_tile<2><<<128,256,0,stream>>>(ff1, w2b, bw2, ffraw, DFF_, D_, 4);

  // 7) final double-LN
  final_kernel<<<M_,256,0,stream>>>(hf, ffraw, gf, bfv, g2, b2, out);
}

// Round 7
// 206.134 us; speedup vs baseline: 2.0365x; 1.0481x over previous
//
#include <hip/hip_runtime.h>
#include <hip/hip_fp16.h>
#include <math.h>

#define B_ 4
#define T_ 1024
#define D_ 512
#define H_ 8
#define HD_ 64
#define KN 30
#define ED_ 128
#define DFF_ 2048
#define M_ 4096   // B*T
#define BH_ 32

typedef _Float16 f16;
typedef __attribute__((ext_vector_type(8))) _Float16 f16x8;
typedef __attribute__((ext_vector_type(4))) _Float16 f16x4;
typedef __attribute__((ext_vector_type(4))) float f32x4;

#define MFMA16 __builtin_amdgcn_mfma_f32_16x16x32_f16
#define LOG2E 1.44269504088896f

__device__ __forceinline__ f16x8 ld8(const f16* p){ return *reinterpret_cast<const f16x8*>(p); }

__device__ __forceinline__ void gld16(const void* g, void* l){
  __builtin_amdgcn_global_load_lds((const __attribute__((address_space(1))) void*)g,
                                   (__attribute__((address_space(3))) void*)l, 16, 0, 0);
}

// ---------------- combined fp32 -> fp16 convert (9 tensors, 1 launch) -------
struct CvtJobs {
  const float* s[9];
  f16* d[9];
  int start[10];   // cumulative block starts; each block = 256 float4s
};

__global__ __launch_bounds__(256) void cvt9_kernel(CvtJobs J){
  const int blk = blockIdx.x;
  int j = 0;
  while (j < 8 && blk >= J.start[j+1]) ++j;
  const int i = (blk - J.start[j])*256 + threadIdx.x;
  float4 v = reinterpret_cast<const float4*>(J.s[j])[i];
  union { f16 h[4]; ushort4 u; } o;
  o.h[0]=(f16)v.x; o.h[1]=(f16)v.y; o.h[2]=(f16)v.z; o.h[3]=(f16)v.w;
  reinterpret_cast<ushort4*>(J.d[j])[i] = o.u;
}

// ---------------- bias prep: f16((bias + mask*-6e4) * rtemp * log2e) --------
// blocks 0..479 also zero the 122880-float g buffer (fused zero_kernel).
__global__ __launch_bounds__(256) void biasprep_kernel(
    const float* __restrict__ bias, const int* __restrict__ mask,
    const float* __restrict__ tsc, f16* __restrict__ biasP,
    float* __restrict__ gzero)
{
  const int gid = blockIdx.x*256 + threadIdx.x;      // 524288 threads, 8 elems each
  if (blockIdx.x < (M_*KN)/256) gzero[gid] = 0.f;
  const float s = exp2f(-2.0f*tanhf(tsc[0]))*LOG2E;  // log2e / 4^tanh(t)
  const int b = gid >> 17;                            // T*T/8 = 131072 per batch
  const int rem = gid & 131071;
  const int idx8 = rem*8;
  const int s0 = idx8 & 1023;
  const size_t gbase = (size_t)b*T_*T_ + idx8;
  float4 v0 = *reinterpret_cast<const float4*>(bias + gbase);
  float4 v1 = *reinterpret_cast<const float4*>(bias + gbase + 4);
  int4 m0 = *reinterpret_cast<const int4*>(mask + b*T_ + s0);
  int4 m1 = *reinterpret_cast<const int4*>(mask + b*T_ + s0 + 4);
  float x[8] = {v0.x,v0.y,v0.z,v0.w,v1.x,v1.y,v1.z,v1.w};
  int  mm[8] = {m0.x,m0.y,m0.z,m0.w,m1.x,m1.y,m1.z,m1.w};
  union { f16 h[8]; ushort4 u[2]; } o;
#pragma unroll
  for (int i = 0; i < 8; ++i){
    float t = (x[i] + (mm[i] ? 0.f : -60000.f))*s;
    o.h[i] = (f16)fmaxf(t, -60000.f);
  }
  reinterpret_cast<ushort4*>(biasP + gbase)[0] = o.u[0];
  reinterpret_cast<ushort4*>(biasP + gbase)[1] = o.u[1];
}

// =============== staged MFMA GEMM (m97 structure): C = X @ W.T ==============
// 128x128 tile. EPI 1: f16 gelu(acc+bias). EPI 2: f32 acc+bias.
template<int EPI>
__global__ __launch_bounds__(256,2) void gemm_tile(
    const f16* __restrict__ X, const f16* __restrict__ W,
    const float* __restrict__ bias, void* __restrict__ outp,
    int Kd, int ldo, int nbN)
{
  __shared__ f16 As[128*32];
  __shared__ f16 Bs[128*32];
  const int nwg = gridDim.x;
  const int bid = blockIdx.x;
  const int swz = (bid & 7)*(nwg >> 3) + (bid >> 3);
  const int mb = swz / nbN, nb = swz - mb*nbN;
  const int rb = mb*128, cb = nb*128;
  const int tid = threadIdx.x;
  const int w = tid >> 6, lane = tid & 63;
  const int l16 = lane & 15, l4 = lane >> 4;
  const int wr = w >> 1, wc = w & 1;
  const int sr = lane >> 2, sc = (lane & 3)*8;
  const f16* Ax0 = X + (size_t)(rb + w*16 + sr)*Kd + sc;
  const f16* Ax1 = X + (size_t)(rb + 64 + w*16 + sr)*Kd + sc;
  const f16* Bx0 = W + (size_t)(cb + w*16 + sr)*Kd + sc;
  const f16* Bx1 = W + (size_t)(cb + 64 + w*16 + sr)*Kd + sc;
  f16* Ad0 = &As[(w*16)*32];
  f16* Ad1 = &As[(64 + w*16)*32];
  f16* Bd0 = &Bs[(w*16)*32];
  f16* Bd1 = &Bs[(64 + w*16)*32];

  f32x4 acc[4][4];
#pragma unroll
  for (int m = 0; m < 4; ++m)
#pragma unroll
    for (int n = 0; n < 4; ++n) acc[m][n] = (f32x4){0.f,0.f,0.f,0.f};

  for (int k0 = 0; k0 < Kd; k0 += 32){
    gld16(Ax0 + k0, Ad0);
    gld16(Ax1 + k0, Ad1);
    gld16(Bx0 + k0, Bd0);
    gld16(Bx1 + k0, Bd1);
    __syncthreads();
    f16x8 a[4], b[4];
#pragma unroll
    for (int m = 0; m < 4; ++m) a[m] = ld8(&As[(wr*64 + m*16 + l16)*32 + l4*8]);
#pragma unroll
    for (int n = 0; n < 4; ++n) b[n] = ld8(&Bs[(wc*64 + n*16 + l16)*32 + l4*8]);
#pragma unroll
    for (int m = 0; m < 4; ++m)
#pragma unroll
      for (int n = 0; n < 4; ++n)
        acc[m][n] = MFMA16(a[m], b[n], acc[m][n], 0,0,0);
    __syncthreads();
  }

#pragma unroll
  for (int n = 0; n < 4; ++n){
    const int col = cb + wc*64 + n*16 + l16;
    const float bv = bias[col];
#pragma unroll
    for (int m = 0; m < 4; ++m){
#pragma unroll
      for (int j = 0; j < 4; ++j){
        const int row = rb + wr*64 + m*16 + l4*4 + j;
        float v = acc[m][n][j] + bv;
        if (EPI == 1){
          v = 0.5f*v*(1.0f + erff(v*0.70710678118654752f));
          ((f16*)outp)[(size_t)row*ldo + col] = (f16)v;
        } else {
          ((float*)outp)[(size_t)row*ldo + col] = v;
        }
      }
    }
  }
}

// =============== 128x64-tile GEMM (2x CU coverage for N=512 outputs) ========
// 4 waves in 2x2; wave tile 64x32 (4x2 frags). EPI semantics as gemm_tile.
template<int EPI>
__global__ __launch_bounds__(256,2) void gemm_n64(
    const f16* __restrict__ X, const f16* __restrict__ W,
    const float* __restrict__ bias, void* __restrict__ outp,
    int Kd, int ldo, int nbN)
{
  __shared__ f16 As[128*32];
  __shared__ f16 Bs[64*32];
  const int nwg = gridDim.x;
  const int bid = blockIdx.x;
  const int swz = (bid & 7)*(nwg >> 3) + (bid >> 3);
  const int mb = swz / nbN, nb = swz - mb*nbN;
  const int rb = mb*128, cb = nb*64;
  const int tid = threadIdx.x;
  const int w = tid >> 6, lane = tid & 63;
  const int l16 = lane & 15, l4 = lane >> 4;
  const int wr = w >> 1, wc = w & 1;
  const int sr = lane >> 2, sc = (lane & 3)*8;
  const f16* Ax0 = X + (size_t)(rb + w*16 + sr)*Kd + sc;
  const f16* Ax1 = X + (size_t)(rb + 64 + w*16 + sr)*Kd + sc;
  const f16* Bx0 = W + (size_t)(cb + w*16 + sr)*Kd + sc;
  f16* Ad0 = &As[(w*16)*32];
  f16* Ad1 = &As[(64 + w*16)*32];
  f16* Bd0 = &Bs[(w*16)*32];

  f32x4 acc[4][2];
#pragma unroll
  for (int m = 0; m < 4; ++m)
#pragma unroll
    for (int n = 0; n < 2; ++n) acc[m][n] = (f32x4){0.f,0.f,0.f,0.f};

  for (int k0 = 0; k0 < Kd; k0 += 32){
    gld16(Ax0 + k0, Ad0);
    gld16(Ax1 + k0, Ad1);
    gld16(Bx0 + k0, Bd0);
    __syncthreads();
    f16x8 a[4], b[2];
#pragma unroll
    for (int m = 0; m < 4; ++m) a[m] = ld8(&As[(wr*64 + m*16 + l16)*32 + l4*8]);
#pragma unroll
    for (int n = 0; n < 2; ++n) b[n] = ld8(&Bs[(wc*32 + n*16 + l16)*32 + l4*8]);
#pragma unroll
    for (int m = 0; m < 4; ++m)
#pragma unroll
      for (int n = 0; n < 2; ++n)
        acc[m][n] = MFMA16(a[m], b[n], acc[m][n], 0,0,0);
    __syncthreads();
  }

#pragma unroll
  for (int n = 0; n < 2; ++n){
    const int col = cb + wc*32 + n*16 + l16;
    const float bv = bias[col];
#pragma unroll
    for (int m = 0; m < 4; ++m){
#pragma unroll
      for (int j = 0; j < 4; ++j){
        const int row = rb + wr*64 + m*16 + l4*4 + j;
        float v = acc[m][n][j] + bv;
        if (EPI == 1){
          v = 0.5f*v*(1.0f + erff(v*0.70710678118654752f));
          ((f16*)outp)[(size_t)row*ldo + col] = (f16)v;
        } else {
          ((float*)outp)[(size_t)row*ldo + col] = v;
        }
      }
    }
  }
}

// =============== batched QKV projection (one launch, 3 GEMMs) ===============
// q epilogue folds 0.125 * rtemp * log2e (exp2-space softmax prescale).
__global__ __launch_bounds__(256,2) void qkv_tile(
    const f16* __restrict__ hV, const f16* __restrict__ kI, const f16* __restrict__ vI,
    const f16* __restrict__ Wq, const f16* __restrict__ Wk, const f16* __restrict__ Wv,
    const float* __restrict__ bq, const float* __restrict__ bk, const float* __restrict__ bv,
    const float* __restrict__ tsc,
    f16* __restrict__ qo, f16* __restrict__ ko, f16* __restrict__ vT)
{
  __shared__ f16 As[128*32];
  __shared__ f16 Bs[128*32];
  const int bid = blockIdx.x;
  const int swz = (bid & 7)*48 + (bid >> 3);
  const int g = swz >> 7;
  const int r = swz & 127;
  const int mb = r >> 2, nb = r & 3;
  const f16* X  = (g == 0) ? hV : ((g == 1) ? kI : vI);
  const f16* W  = (g == 0) ? Wq : ((g == 1) ? Wk : Wv);
  const float* bias = (g == 0) ? bq : ((g == 1) ? bk : bv);
  const int rb = mb*128, cb = nb*128;
  const int tid = threadIdx.x;
  const int w = tid >> 6, lane = tid & 63;
  const int l16 = lane & 15, l4 = lane >> 4;
  const int wr = w >> 1, wc = w & 1;
  const int sr = lane >> 2, sc = (lane & 3)*8;
  const f16* Ax0 = X + (size_t)(rb + w*16 + sr)*D_ + sc;
  const f16* Ax1 = X + (size_t)(rb + 64 + w*16 + sr)*D_ + sc;
  const f16* Bx0 = W + (size_t)(cb + w*16 + sr)*D_ + sc;
  const f16* Bx1 = W + (size_t)(cb + 64 + w*16 + sr)*D_ + sc;
  f16* Ad0 = &As[(w*16)*32];
  f16* Ad1 = &As[(64 + w*16)*32];
  f16* Bd0 = &Bs[(w*16)*32];
  f16* Bd1 = &Bs[(64 + w*16)*32];

  f32x4 acc[4][4];
#pragma unroll
  for (int m = 0; m < 4; ++m)
#pragma unroll
    for (int n = 0; n < 4; ++n) acc[m][n] = (f32x4){0.f,0.f,0.f,0.f};

  for (int k0 = 0; k0 < D_; k0 += 32){
    gld16(Ax0 + k0, Ad0);
    gld16(Ax1 + k0, Ad1);
    gld16(Bx0 + k0, Bd0);
    gld16(Bx1 + k0, Bd1);
    __syncthreads();
    f16x8 a[4], b[4];
#pragma unroll
    for (int m = 0; m < 4; ++m) a[m] = ld8(&As[(wr*64 + m*16 + l16)*32 + l4*8]);
#pragma unroll
    for (int n = 0; n < 4; ++n) b[n] = ld8(&Bs[(wc*64 + n*16 + l16)*32 + l4*8]);
#pragma unroll
    for (int m = 0; m < 4; ++m)
#pragma unroll
      for (int n = 0; n < 4; ++n)
        acc[m][n] = MFMA16(a[m], b[n], acc[m][n], 0,0,0);
    __syncthreads();
  }

  const float qs = exp2f(-2.0f*tanhf(tsc[0]))*LOG2E*0.125f;
  const float scale = (g == 0) ? qs : 1.0f;
  f16* out = (g == 0) ? qo : ko;
#pragma unroll
  for (int n = 0; n < 4; ++n){
    const int col = cb + wc*64 + n*16 + l16;
    const float bv = bias[col];
#pragma unroll
    for (int m = 0; m < 4; ++m){
#pragma unroll
      for (int j = 0; j < 4; ++j){
        const int row = rb + wr*64 + m*16 + l4*4 + j;
        const float v = (acc[m][n][j] + bv)*scale;
        if (g < 2){
          out[(size_t)row*D_ + col] = (f16)v;
        } else {
          const int b = row >> 10, t = row & (T_-1);
          const int h = col >> 6,  dl = col & (HD_-1);
          vT[(((size_t)b*H_ + h)*HD_ + dl)*T_ + t] = (f16)v;
        }
      }
    }
  }
}

// =============== fused attention: QK^T(swapped) + softmax + PV + gather =====
// block = 16 q-rows x one (b,h); 4 waves; wave w owns s-range [w*256,+256)
// for QK and d-cols [w*16,+16) for PV. Scores live in registers; P staged
// unnormalized f16 in LDS (stride 1032, 16B-aligned rows, ~2-way banked).
// PV = 4 independent MFMA chains (8-deep) with vT chain-start prefetch
// hoisted above the P barrier; bias staged via async global_load_lds.
#define PSTR 1032
__global__ __launch_bounds__(256,4) void attn_fused(
    const f16* __restrict__ q, const f16* __restrict__ k, const f16* __restrict__ vT,
    const f16* __restrict__ biasP, const int* __restrict__ eidx,
    f16* __restrict__ X2, float* __restrict__ gout)
{
  __shared__ f16 Pb[16*PSTR];
  __shared__ float red[2][4][16];
  const int bid = blockIdx.x;
  const int swz = (bid & 7)*256 + (bid >> 3);   // XCD gets 4 contiguous bh
  const int bh = swz >> 6, tb = swz & 63;
  const int bi = bh >> 3, h = bh & 7;
  const int t0 = tb*16;
  const int tid = threadIdx.x, w = tid >> 6, lane = tid & 63;
  const int l16 = lane & 15, l4 = lane >> 4;

  // ---- stage bias tile [16][1024] f16 -> Pb via async global_load_lds ----
  // wave w stages rows [w*4, w*4+4); each row-half (512 f16 = 1 KB) is
  // LDS-linear (base + lane*16B), so gld16's uniform-dest rule holds.
  {
    const f16* bsrc = biasP + ((size_t)(bi*T_ + t0))*T_;
#pragma unroll
    for (int r = 0; r < 4; ++r){
      const int row = w*4 + r;
#pragma unroll
      for (int half = 0; half < 2; ++half){
        gld16(bsrc + (size_t)row*T_ + half*512 + lane*8,
              &Pb[row*PSTR + half*512]);
      }
    }
  }
  __syncthreads();

  // ---- QK^T swapped: acc[c][j] = S[s = sbase+c*16+l4*4+j][q = l16] ----
  const f16* qp = q + (size_t)(bi*T_ + t0 + l16)*D_ + h*HD_ + l4*8;
  const f16x8 q0 = ld8(qp), q1 = ld8(qp + 32);
  const int sbase = w*256;
  f32x4 acc[16];
#pragma unroll
  for (int c = 0; c < 16; ++c){
    const f16* kp = k + (size_t)(bi*T_ + sbase + c*16 + l16)*D_ + h*HD_ + l4*8;
    f32x4 a = {0.f,0.f,0.f,0.f};
    a = MFMA16(ld8(kp),      q0, a, 0,0,0);
    a = MFMA16(ld8(kp + 32), q1, a, 0,0,0);
    const f16x4 bfrg = *reinterpret_cast<const f16x4*>(&Pb[l16*PSTR + sbase + c*16 + l4*4]);
#pragma unroll
    for (int j = 0; j < 4; ++j) a[j] += (float)bfrg[j];
    acc[c] = a;
  }

  // ---- row max: in-lane (64 vals, one q-row per lane) + shfl + cross-wave --
  float m = -3.4e38f;
#pragma unroll
  for (int c = 0; c < 16; ++c)
#pragma unroll
    for (int j = 0; j < 4; ++j) m = fmaxf(m, acc[c][j]);
  m = fmaxf(m, __shfl_xor(m, 16));
  m = fmaxf(m, __shfl_xor(m, 32));
  if (lane < 16) red[0][w][lane] = m;
  __syncthreads();
  m = fmaxf(fmaxf(red[0][0][l16], red[0][1][l16]),
            fmaxf(red[0][2][l16], red[0][3][l16]));

  // ---- exp2, accumulate l, pack unnormalized P to LDS ----
  float l = 0.f;
#pragma unroll
  for (int c = 0; c < 16; ++c){
    f16x4 pp;
#pragma unroll
    for (int j = 0; j < 4; ++j){
      const float e = exp2f(acc[c][j] - m);
      l += e;
      pp[j] = (f16)e;
    }
    *reinterpret_cast<f16x4*>(&Pb[l16*PSTR + sbase + c*16 + l4*4]) = pp;
  }
  l += __shfl_xor(l, 16);
  l += __shfl_xor(l, 32);
  if (lane < 16) red[1][w][lane] = l;

  // ---- prefetch vT chain-start frags (global, independent of P) ----
  const f16* vp = vT + ((size_t)bh*HD_ + w*16 + l16)*T_ + l4*8;
  f16x8 vp0 = ld8(vp), vp1 = ld8(vp + 32), vp2 = ld8(vp + 64), vp3 = ld8(vp + 96);
  __syncthreads();   // P writes + partial sums all visible

  // ---- PV: wave w -> d-cols [w*16,+16); 4 independent 8-deep MFMA chains --
  f32x4 oo0 = {0.f,0.f,0.f,0.f}, oo1 = oo0, oo2 = oo0, oo3 = oo0;
  {
    const int qr = l16*PSTR + l4*8;
    oo0 = MFMA16(*reinterpret_cast<const f16x8*>(&Pb[qr]),      vp0, oo0, 0,0,0);
    oo1 = MFMA16(*reinterpret_cast<const f16x8*>(&Pb[qr + 32]), vp1, oo1, 0,0,0);
    oo2 = MFMA16(*reinterpret_cast<const f16x8*>(&Pb[qr + 64]), vp2, oo2, 0,0,0);
    oo3 = MFMA16(*reinterpret_cast<const f16x8*>(&Pb[qr + 96]), vp3, oo3, 0,0,0);
  }
#pragma unroll
  for (int s0 = 128; s0 < T_; s0 += 128){
    const int qr = l16*PSTR + s0 + l4*8;
    oo0 = MFMA16(*reinterpret_cast<const f16x8*>(&Pb[qr]),      ld8(vp + s0),      oo0, 0,0,0);
    oo1 = MFMA16(*reinterpret_cast<const f16x8*>(&Pb[qr + 32]), ld8(vp + s0 + 32), oo1, 0,0,0);
    oo2 = MFMA16(*reinterpret_cast<const f16x8*>(&Pb[qr + 64]), ld8(vp + s0 + 64), oo2, 0,0,0);
    oo3 = MFMA16(*reinterpret_cast<const f16x8*>(&Pb[qr + 96]), ld8(vp + s0 + 96), oo3, 0,0,0);
  }
  const f32x4 o = (oo0 + oo1) + (oo2 + oo3);

#pragma unroll
  for (int j = 0; j < 4; ++j){
    const int row = l4*4 + j;
    const float lr = red[1][0][row] + red[1][1][row] + red[1][2][row] + red[1][3][row];
    const int t = t0 + row;
    X2[((size_t)(bi*T_ + t))*640 + h*HD_ + w*16 + l16] = (f16)(o[j]/lr);
  }

  // ---- edge gather: g[b,t,kk] += p_norm / H  (480 items, strided loop) ----
  for (int jj = tid; jj < 16*KN; jj += 256){
    const int r = jj/KN, kk = jj - r*KN;
    const float lr = red[1][0][r] + red[1][1][r] + red[1][2][r] + red[1][3][r];
    const int t = t0 + r;
    const int id = eidx[((size_t)(bi*T_ + t))*KN + kk];
    const float pv = (float)Pb[r*PSTR + id];
    atomicAdd(&gout[((size_t)(bi*T_ + t))*KN + kk], pv/lr*0.125f);
  }
}

// ---------------- edge: weighted neighbor-embedding mean -------------------
__global__ __launch_bounds__(128) void edge_kernel(
    const float* __restrict__ g, const float* __restrict__ E, f16* __restrict__ X2)
{
  __shared__ float gl[KN];
  __shared__ float ginv;
  const int bt = blockIdx.x;
  const int t = threadIdx.x;
  if (t < KN) gl[t] = g[(size_t)bt*KN + t];
  __syncthreads();
  if (t == 0){
    float s = 0.f;
#pragma unroll
    for (int i = 0; i < KN; ++i) s += gl[i];
    ginv = 1.0f/(s + 1e-6f);
  }
  __syncthreads();
  float acc = 0.f;
  const float* Ep = E + (size_t)bt*KN*ED_ + t;
#pragma unroll 5
  for (int kk = 0; kk < KN; ++kk) acc += gl[kk]*Ep[(size_t)kk*ED_];
  X2[(size_t)bt*640 + 512 + t] = (f16)(acc*ginv);
}

// ---------------- LayerNorm helpers ----------------------------------------
__device__ __forceinline__ float block_sum(float v, float* sbuf){
  for (int o = 32; o; o >>= 1) v += __shfl_down(v, o);
  __syncthreads();
  if ((threadIdx.x & 63) == 0) sbuf[threadIdx.x >> 6] = v;
  __syncthreads();
  return sbuf[0]+sbuf[1]+sbuf[2]+sbuf[3];
}

__global__ __launch_bounds__(256) void ln1_kernel(
    const float* __restrict__ hV, const float* __restrict__ hraw,
    const float* __restrict__ gn, const float* __restrict__ bn,
    float* __restrict__ hf, f16* __restrict__ hh)
{
  __shared__ float sbuf[4];
  const int r = blockIdx.x, t = threadIdx.x;
  const size_t base = (size_t)r*D_;
  float x0 = hV[base+t]     + hraw[base+t];
  float x1 = hV[base+t+256] + hraw[base+t+256];
  float s = block_sum(x0+x1, sbuf);
  const float mean = s*(1.f/512.f);
  float d0 = x0-mean, d1 = x1-mean;
  float vs = block_sum(d0*d0+d1*d1, sbuf);
  const float rstd = rsqrtf(vs*(1.f/512.f) + 1e-5f);
  float y0 = d0*rstd*gn[t]     + bn[t];
  float y1 = d1*rstd*gn[t+256] + bn[t+256];
  hf[base+t]     = y0;  hh[base+t]     = (f16)y0;
  hf[base+t+256] = y1;  hh[base+t+256] = (f16)y1;
}

__global__ __launch_bounds__(256) void final_kernel(
    const float* __restrict__ hf, const float* __restrict__ ffr,
    const float* __restrict__ gf, const float* __restrict__ bfv,
    const float* __restrict__ g2, const float* __restrict__ b2,
    float* __restrict__ out)
{
  __shared__ float sbuf[4];
  const int r = blockIdx.x, t = threadIdx.x;
  const size_t base = (size_t)r*D_;
  const float h0 = hf[base+t], h1 = hf[base+t+256];
  float x0 = h0 + ffr[base+t], x1 = h1 + ffr[base+t+256];
  float s = block_sum(x0+x1, sbuf);
  float mean = s*(1.f/512.f);
  float d0 = x0-mean, d1 = x1-mean;
  float vs = block_sum(d0*d0+d1*d1, sbuf);
  float rstd = rsqrtf(vs*(1.f/512.f) + 1e-6f);
  const float dh0 = d0*rstd*gf[t]     + bfv[t];
  const float dh1 = d1*rstd*gf[t+256] + bfv[t+256];
  const float y0 = h0 + dh0, y1 = h1 + dh1;
  s = block_sum(y0+y1, sbuf);
  mean = s*(1.f/512.f);
  d0 = y0-mean; d1 = y1-mean;
  vs = block_sum(d0*d0+d1*d1, sbuf);
  rstd = rsqrtf(vs*(1.f/512.f) + 1e-5f);
  out[base+t]     = d0*rstd*g2[t]     + b2[t];
  out[base+t+256] = d1*rstd*g2[t+256] + b2[t+256];
}

// ---------------------------------------------------------------------------
extern "C" void kernel_launch(void* const* d_in, const int* in_sizes, int n_in,
                              void* d_out, int out_size, void* d_ws, size_t ws_size,
                              hipStream_t stream)
{
  (void)in_sizes; (void)n_in; (void)out_size;
  const float* h_V  = (const float*)d_in[0];
  const float* kin  = (const float*)d_in[1];
  const float* vin  = (const float*)d_in[2];
  const float* E    = (const float*)d_in[3];
  const float* bias = (const float*)d_in[4];
  const float* Wq   = (const float*)d_in[5];
  const float* bq   = (const float*)d_in[6];
  const float* Wk   = (const float*)d_in[7];
  const float* bk   = (const float*)d_in[8];
  const float* Wv   = (const float*)d_in[9];
  const float* bv   = (const float*)d_in[10];
  const float* Wo   = (const float*)d_in[11];
  const float* bo   = (const float*)d_in[12];
  const float* tsc  = (const float*)d_in[13];
  const float* gn   = (const float*)d_in[14];
  const float* bn   = (const float*)d_in[15];
  const float* w1   = (const float*)d_in[16];
  const float* bw1  = (const float*)d_in[17];
  const float* w2   = (const float*)d_in[18];
  const float* bw2  = (const float*)d_in[19];
  const float* gf   = (const float*)d_in[20];
  const float* bfv  = (const float*)d_in[21];
  const float* g2   = (const float*)d_in[22];
  const float* b2   = (const float*)d_in[23];
  const int*   Eidx = (const int*)d_in[24];
  const int*   mask = (const int*)d_in[25];
  float* out = (float*)d_out;

  char* wsb = (char*)d_ws;
  size_t off = 0;
  auto alloc = [&](size_t bytes) -> void* {
    void* pp = wsb + off; off += (bytes + 255) & ~(size_t)255; return pp;
  };
  f16* hVb  = (f16*)alloc((size_t)M_*D_*2);
  f16* kbI  = (f16*)alloc((size_t)M_*D_*2);
  f16* vbI  = (f16*)alloc((size_t)M_*D_*2);
  f16* Wqb  = (f16*)alloc((size_t)D_*D_*2);
  f16* Wkb  = (f16*)alloc((size_t)D_*D_*2);
  f16* Wvb  = (f16*)alloc((size_t)D_*D_*2);
  f16* Wob  = (f16*)alloc((size_t)D_*(D_+ED_)*2);
  f16* w1b  = (f16*)alloc((size_t)DFF_*D_*2);
  f16* w2b  = (f16*)alloc((size_t)D_*DFF_*2);
  f16* qb   = (f16*)alloc((size_t)M_*D_*2);
  f16* kb   = (f16*)alloc((size_t)M_*D_*2);
  f16* vT   = (f16*)alloc((size_t)M_*D_*2);
  f16* biasP= (f16*)alloc((size_t)B_*T_*T_*2);
  f16* X2   = (f16*)alloc((size_t)M_*640*2);
  float* gbuf = (float*)alloc((size_t)M_*KN*4);
  float* hraw = (float*)alloc((size_t)M_*D_*4);   // reused as ffraw
  float* hf   = (float*)alloc((size_t)M_*D_*4);
  f16*   hh   = (f16*)alloc((size_t)M_*D_*2);
  f16*   ff1  = (f16*)alloc((size_t)M_*DFF_*2);
  if (ws_size < off) return;  // scratch insufficient -> loud validation failure
  float* ffraw = hraw;

  // 1) converts fp32 -> f16 (one launch) + bias prep (fused g-zero)
  {
    CvtJobs J;
    const float* srcs[9] = {h_V, kin, vin, Wq, Wk, Wv, Wo, w1, w2};
    f16* dsts[9] = {hVb, kbI, vbI, Wqb, Wkb, Wvb, Wob, w1b, w2b};
    const int n4s[9] = {M_*D_/4, M_*D_/4, M_*D_/4, D_*D_/4, D_*D_/4, D_*D_/4,
                        D_*(D_+ED_)/4, DFF_*D_/4, D_*DFF_/4};
    int cum = 0;
    for (int i = 0; i < 9; ++i){
      J.s[i] = srcs[i]; J.d[i] = dsts[i]; J.start[i] = cum;
      cum += n4s[i]/256;
    }
    J.start[9] = cum;
    cvt9_kernel<<<cum,256,0,stream>>>(J);
  }
  biasprep_kernel<<<B_*T_*T_/8/256,256,0,stream>>>(bias, mask, tsc, biasP, gbuf);

  // 2) batched q/k/v projections (q pre-scaled for exp2 softmax; v -> vT)
  qkv_tile<<<384,256,0,stream>>>(hVb, kbI, vbI, Wqb, Wkb, Wvb, bq, bk, bv, tsc, qb, kb, vT);

  // 3) fused attention (QK^T + softmax + PV + edge gather)
  attn_fused<<<2048,256,0,stream>>>(qb, kb, vT, biasP, Eidx, X2, gbuf);

  // 4) edge embedding
  edge_kernel<<<M_,128,0,stream>>>(gbuf, E, X2);

  // 5) out-proj (128x64 tiles, 256 blocks) + residual LN
  gemm_n64<2><<<256,256,0,stream>>>(X2, Wob, bo, hraw, D_+ED_, D_, 8);
  ln1_kernel<<<M_,256,0,stream>>>(h_V, hraw, gn, bn, hf, hh);

  // 6) FFN: FF1 128x128 (512 blocks), FF2 128x64 (256 blocks)
  gemm_tile<1><<<512,256,0,stream>>>(hh, w1b, bw1, ff1, D_, DFF_, 16);
  gemm_n64<2><<<256,256,0,stream>>>(ff1, w2b, bw2, ffraw, DFF_, D_, 8);

  // 7) final double-LN
  final_kernel<<<M_,256,0,stream>>>(hf, ffraw, gf, bfv, g2, b2, out);
}

// Round 8
// 203.651 us; speedup vs baseline: 2.0614x; 1.0122x over previous
//
#include <hip/hip_runtime.h>
#include <hip/hip_fp16.h>
#include <math.h>

#define B_ 4
#define T_ 1024
#define D_ 512
#define H_ 8
#define HD_ 64
#define KN 30
#define ED_ 128
#define DFF_ 2048
#define M_ 4096   // B*T
#define BH_ 32

typedef _Float16 f16;
typedef __attribute__((ext_vector_type(8))) _Float16 f16x8;
typedef __attribute__((ext_vector_type(4))) _Float16 f16x4;
typedef __attribute__((ext_vector_type(4))) float f32x4;

#define MFMA16 __builtin_amdgcn_mfma_f32_16x16x32_f16
#define LOG2E 1.44269504088896f

__device__ __forceinline__ f16x8 ld8(const f16* p){ return *reinterpret_cast<const f16x8*>(p); }

__device__ __forceinline__ void gld16(const void* g, void* l){
  __builtin_amdgcn_global_load_lds((const __attribute__((address_space(1))) void*)g,
                                   (__attribute__((address_space(3))) void*)l, 16, 0, 0);
}

// ---------------- combined fp32 -> fp16 convert (9 tensors, 1 launch) -------
struct CvtJobs {
  const float* s[9];
  f16* d[9];
  int start[10];   // cumulative block starts; each block = 256 float4s
};

__global__ __launch_bounds__(256) void cvt9_kernel(CvtJobs J){
  const int blk = blockIdx.x;
  int j = 0;
  while (j < 8 && blk >= J.start[j+1]) ++j;
  const int i = (blk - J.start[j])*256 + threadIdx.x;
  float4 v = reinterpret_cast<const float4*>(J.s[j])[i];
  union { f16 h[4]; ushort4 u; } o;
  o.h[0]=(f16)v.x; o.h[1]=(f16)v.y; o.h[2]=(f16)v.z; o.h[3]=(f16)v.w;
  reinterpret_cast<ushort4*>(J.d[j])[i] = o.u;
}

// ---------------- bias prep: f16((bias + mask*-6e4) * rtemp * log2e) --------
// blocks 0..479 also zero the 122880-float g buffer (fused zero_kernel).
__global__ __launch_bounds__(256) void biasprep_kernel(
    const float* __restrict__ bias, const int* __restrict__ mask,
    const float* __restrict__ tsc, f16* __restrict__ biasP,
    float* __restrict__ gzero)
{
  const int gid = blockIdx.x*256 + threadIdx.x;      // 524288 threads, 8 elems each
  if (blockIdx.x < (M_*KN)/256) gzero[gid] = 0.f;
  const float s = exp2f(-2.0f*tanhf(tsc[0]))*LOG2E;  // log2e / 4^tanh(t)
  const int b = gid >> 17;                            // T*T/8 = 131072 per batch
  const int rem = gid & 131071;
  const int idx8 = rem*8;
  const int s0 = idx8 & 1023;
  const size_t gbase = (size_t)b*T_*T_ + idx8;
  float4 v0 = *reinterpret_cast<const float4*>(bias + gbase);
  float4 v1 = *reinterpret_cast<const float4*>(bias + gbase + 4);
  int4 m0 = *reinterpret_cast<const int4*>(mask + b*T_ + s0);
  int4 m1 = *reinterpret_cast<const int4*>(mask + b*T_ + s0 + 4);
  float x[8] = {v0.x,v0.y,v0.z,v0.w,v1.x,v1.y,v1.z,v1.w};
  int  mm[8] = {m0.x,m0.y,m0.z,m0.w,m1.x,m1.y,m1.z,m1.w};
  union { f16 h[8]; ushort4 u[2]; } o;
#pragma unroll
  for (int i = 0; i < 8; ++i){
    float t = (x[i] + (mm[i] ? 0.f : -60000.f))*s;
    o.h[i] = (f16)fmaxf(t, -60000.f);
  }
  reinterpret_cast<ushort4*>(biasP + gbase)[0] = o.u[0];
  reinterpret_cast<ushort4*>(biasP + gbase)[1] = o.u[1];
}

// =============== staged MFMA GEMM (m97 structure): C = X @ W.T ==============
// 128x128 tile. EPI 1: f16 gelu(acc+bias). EPI 2: f32 acc+bias.
template<int EPI>
__global__ __launch_bounds__(256,2) void gemm_tile(
    const f16* __restrict__ X, const f16* __restrict__ W,
    const float* __restrict__ bias, void* __restrict__ outp,
    int Kd, int ldo, int nbN)
{
  __shared__ f16 As[128*32];
  __shared__ f16 Bs[128*32];
  const int nwg = gridDim.x;
  const int bid = blockIdx.x;
  const int swz = (bid & 7)*(nwg >> 3) + (bid >> 3);
  const int mb = swz / nbN, nb = swz - mb*nbN;
  const int rb = mb*128, cb = nb*128;
  const int tid = threadIdx.x;
  const int w = tid >> 6, lane = tid & 63;
  const int l16 = lane & 15, l4 = lane >> 4;
  const int wr = w >> 1, wc = w & 1;
  const int sr = lane >> 2, sc = (lane & 3)*8;
  const f16* Ax0 = X + (size_t)(rb + w*16 + sr)*Kd + sc;
  const f16* Ax1 = X + (size_t)(rb + 64 + w*16 + sr)*Kd + sc;
  const f16* Bx0 = W + (size_t)(cb + w*16 + sr)*Kd + sc;
  const f16* Bx1 = W + (size_t)(cb + 64 + w*16 + sr)*Kd + sc;
  f16* Ad0 = &As[(w*16)*32];
  f16* Ad1 = &As[(64 + w*16)*32];
  f16* Bd0 = &Bs[(w*16)*32];
  f16* Bd1 = &Bs[(64 + w*16)*32];

  f32x4 acc[4][4];
#pragma unroll
  for (int m = 0; m < 4; ++m)
#pragma unroll
    for (int n = 0; n < 4; ++n) acc[m][n] = (f32x4){0.f,0.f,0.f,0.f};

  for (int k0 = 0; k0 < Kd; k0 += 32){
    gld16(Ax0 + k0, Ad0);
    gld16(Ax1 + k0, Ad1);
    gld16(Bx0 + k0, Bd0);
    gld16(Bx1 + k0, Bd1);
    __syncthreads();
    f16x8 a[4], b[4];
#pragma unroll
    for (int m = 0; m < 4; ++m) a[m] = ld8(&As[(wr*64 + m*16 + l16)*32 + l4*8]);
#pragma unroll
    for (int n = 0; n < 4; ++n) b[n] = ld8(&Bs[(wc*64 + n*16 + l16)*32 + l4*8]);
#pragma unroll
    for (int m = 0; m < 4; ++m)
#pragma unroll
      for (int n = 0; n < 4; ++n)
        acc[m][n] = MFMA16(a[m], b[n], acc[m][n], 0,0,0);
    __syncthreads();
  }

#pragma unroll
  for (int n = 0; n < 4; ++n){
    const int col = cb + wc*64 + n*16 + l16;
    const float bv = bias[col];
#pragma unroll
    for (int m = 0; m < 4; ++m){
#pragma unroll
      for (int j = 0; j < 4; ++j){
        const int row = rb + wr*64 + m*16 + l4*4 + j;
        float v = acc[m][n][j] + bv;
        if (EPI == 1){
          v = 0.5f*v*(1.0f + erff(v*0.70710678118654752f));
          ((f16*)outp)[(size_t)row*ldo + col] = (f16)v;
        } else {
          ((float*)outp)[(size_t)row*ldo + col] = v;
        }
      }
    }
  }
}

// =============== 128x64-tile GEMM (2x CU coverage for N=512 outputs) ========
template<int EPI>
__global__ __launch_bounds__(256,2) void gemm_n64(
    const f16* __restrict__ X, const f16* __restrict__ W,
    const float* __restrict__ bias, void* __restrict__ outp,
    int Kd, int ldo, int nbN)
{
  __shared__ f16 As[128*32];
  __shared__ f16 Bs[64*32];
  const int nwg = gridDim.x;
  const int bid = blockIdx.x;
  const int swz = (bid & 7)*(nwg >> 3) + (bid >> 3);
  const int mb = swz / nbN, nb = swz - mb*nbN;
  const int rb = mb*128, cb = nb*64;
  const int tid = threadIdx.x;
  const int w = tid >> 6, lane = tid & 63;
  const int l16 = lane & 15, l4 = lane >> 4;
  const int wr = w >> 1, wc = w & 1;
  const int sr = lane >> 2, sc = (lane & 3)*8;
  const f16* Ax0 = X + (size_t)(rb + w*16 + sr)*Kd + sc;
  const f16* Ax1 = X + (size_t)(rb + 64 + w*16 + sr)*Kd + sc;
  const f16* Bx0 = W + (size_t)(cb + w*16 + sr)*Kd + sc;
  f16* Ad0 = &As[(w*16)*32];
  f16* Ad1 = &As[(64 + w*16)*32];
  f16* Bd0 = &Bs[(w*16)*32];

  f32x4 acc[4][2];
#pragma unroll
  for (int m = 0; m < 4; ++m)
#pragma unroll
    for (int n = 0; n < 2; ++n) acc[m][n] = (f32x4){0.f,0.f,0.f,0.f};

  for (int k0 = 0; k0 < Kd; k0 += 32){
    gld16(Ax0 + k0, Ad0);
    gld16(Ax1 + k0, Ad1);
    gld16(Bx0 + k0, Bd0);
    __syncthreads();
    f16x8 a[4], b[2];
#pragma unroll
    for (int m = 0; m < 4; ++m) a[m] = ld8(&As[(wr*64 + m*16 + l16)*32 + l4*8]);
#pragma unroll
    for (int n = 0; n < 2; ++n) b[n] = ld8(&Bs[(wc*32 + n*16 + l16)*32 + l4*8]);
#pragma unroll
    for (int m = 0; m < 4; ++m)
#pragma unroll
      for (int n = 0; n < 2; ++n)
        acc[m][n] = MFMA16(a[m], b[n], acc[m][n], 0,0,0);
    __syncthreads();
  }

#pragma unroll
  for (int n = 0; n < 2; ++n){
    const int col = cb + wc*32 + n*16 + l16;
    const float bv = bias[col];
#pragma unroll
    for (int m = 0; m < 4; ++m){
#pragma unroll
      for (int j = 0; j < 4; ++j){
        const int row = rb + wr*64 + m*16 + l4*4 + j;
        float v = acc[m][n][j] + bv;
        if (EPI == 1){
          v = 0.5f*v*(1.0f + erff(v*0.70710678118654752f));
          ((f16*)outp)[(size_t)row*ldo + col] = (f16)v;
        } else {
          ((float*)outp)[(size_t)row*ldo + col] = v;
        }
      }
    }
  }
}

// =============== batched QKV projection (one launch, 3 GEMMs) ===============
__global__ __launch_bounds__(256,2) void qkv_tile(
    const f16* __restrict__ hV, const f16* __restrict__ kI, const f16* __restrict__ vI,
    const f16* __restrict__ Wq, const f16* __restrict__ Wk, const f16* __restrict__ Wv,
    const float* __restrict__ bq, const float* __restrict__ bk, const float* __restrict__ bv,
    const float* __restrict__ tsc,
    f16* __restrict__ qo, f16* __restrict__ ko, f16* __restrict__ vT)
{
  __shared__ f16 As[128*32];
  __shared__ f16 Bs[128*32];
  const int bid = blockIdx.x;
  const int swz = (bid & 7)*48 + (bid >> 3);
  const int g = swz >> 7;
  const int r = swz & 127;
  const int mb = r >> 2, nb = r & 3;
  const f16* X  = (g == 0) ? hV : ((g == 1) ? kI : vI);
  const f16* W  = (g == 0) ? Wq : ((g == 1) ? Wk : Wv);
  const float* bias = (g == 0) ? bq : ((g == 1) ? bk : bv);
  const int rb = mb*128, cb = nb*128;
  const int tid = threadIdx.x;
  const int w = tid >> 6, lane = tid & 63;
  const int l16 = lane & 15, l4 = lane >> 4;
  const int wr = w >> 1, wc = w & 1;
  const int sr = lane >> 2, sc = (lane & 3)*8;
  const f16* Ax0 = X + (size_t)(rb + w*16 + sr)*D_ + sc;
  const f16* Ax1 = X + (size_t)(rb + 64 + w*16 + sr)*D_ + sc;
  const f16* Bx0 = W + (size_t)(cb + w*16 + sr)*D_ + sc;
  const f16* Bx1 = W + (size_t)(cb + 64 + w*16 + sr)*D_ + sc;
  f16* Ad0 = &As[(w*16)*32];
  f16* Ad1 = &As[(64 + w*16)*32];
  f16* Bd0 = &Bs[(w*16)*32];
  f16* Bd1 = &Bs[(64 + w*16)*32];

  f32x4 acc[4][4];
#pragma unroll
  for (int m = 0; m < 4; ++m)
#pragma unroll
    for (int n = 0; n < 4; ++n) acc[m][n] = (f32x4){0.f,0.f,0.f,0.f};

  for (int k0 = 0; k0 < D_; k0 += 32){
    gld16(Ax0 + k0, Ad0);
    gld16(Ax1 + k0, Ad1);
    gld16(Bx0 + k0, Bd0);
    gld16(Bx1 + k0, Bd1);
    __syncthreads();
    f16x8 a[4], b[4];
#pragma unroll
    for (int m = 0; m < 4; ++m) a[m] = ld8(&As[(wr*64 + m*16 + l16)*32 + l4*8]);
#pragma unroll
    for (int n = 0; n < 4; ++n) b[n] = ld8(&Bs[(wc*64 + n*16 + l16)*32 + l4*8]);
#pragma unroll
    for (int m = 0; m < 4; ++m)
#pragma unroll
      for (int n = 0; n < 4; ++n)
        acc[m][n] = MFMA16(a[m], b[n], acc[m][n], 0,0,0);
    __syncthreads();
  }

  const float qs = exp2f(-2.0f*tanhf(tsc[0]))*LOG2E*0.125f;
  const float scale = (g == 0) ? qs : 1.0f;
  f16* out = (g == 0) ? qo : ko;
#pragma unroll
  for (int n = 0; n < 4; ++n){
    const int col = cb + wc*64 + n*16 + l16;
    const float bv = bias[col];
#pragma unroll
    for (int m = 0; m < 4; ++m){
#pragma unroll
      for (int j = 0; j < 4; ++j){
        const int row = rb + wr*64 + m*16 + l4*4 + j;
        const float v = (acc[m][n][j] + bv)*scale;
        if (g < 2){
          out[(size_t)row*D_ + col] = (f16)v;
        } else {
          const int b = row >> 10, t = row & (T_-1);
          const int h = col >> 6,  dl = col & (HD_-1);
          vT[(((size_t)b*H_ + h)*HD_ + dl)*T_ + t] = (f16)v;
        }
      }
    }
  }
}

// =============== fused attention: QK^T(swapped) + softmax + PV + gather =====
// block = 16 q-rows x one (b,h); 4 waves; wave w owns s-range [w*256,+256)
// for QK and d-cols [w*16,+16) for PV. K and V are staged through LDS with
// coalesced global_load_lds + XOR swizzle (byte chunk ^= row&7, pre-swizzled
// global source since gld16 writes linearly); P unnormalized f16 in LDS.
#define PSTR 1032
__global__ __launch_bounds__(256,2) void attn_fused(
    const f16* __restrict__ q, const f16* __restrict__ k, const f16* __restrict__ vT,
    const f16* __restrict__ biasP, const int* __restrict__ eidx,
    f16* __restrict__ X2, float* __restrict__ gout)
{
  __shared__ f16 Pb[16*PSTR];     // bias tile, then unnormalized P (33 KB)
  __shared__ f16 Kb[64*64];       // K step tile: 4 groups x 16 s-rows x 64 d (8 KB)
  __shared__ f16 Vb[64*128];      // V chunk tile: 64 d x 128 s (16 KB)
  __shared__ float red[2][4][16];
  const int bid = blockIdx.x;
  const int swz = (bid & 7)*256 + (bid >> 3);   // XCD gets 4 contiguous bh
  const int bh = swz >> 6, tb = swz & 63;
  const int bi = bh >> 3, h = bh & 7;
  const int t0 = tb*16;
  const int tid = threadIdx.x, w = tid >> 6, lane = tid & 63;
  const int l16 = lane & 15, l4 = lane >> 4;

  // ---- stage bias tile [16][1024] f16 -> Pb via async global_load_lds ----
  {
    const f16* bsrc = biasP + ((size_t)(bi*T_ + t0))*T_;
#pragma unroll
    for (int r = 0; r < 4; ++r){
      const int row = w*4 + r;
#pragma unroll
      for (int half = 0; half < 2; ++half){
        gld16(bsrc + (size_t)row*T_ + half*512 + lane*8,
              &Pb[row*PSTR + half*512]);
      }
    }
  }

  // ---- Q fragments (2 scatter loads only) ----
  const f16* qp = q + (size_t)(bi*T_ + t0 + l16)*D_ + h*HD_ + l4*8;
  const f16x8 q0 = ld8(qp), q1 = ld8(qp + 32);

  // ---- QK^T with K staged through LDS (m97 2-barrier pattern) ----
  // wave w stages its own 16-row group each step; swizzle: chunk ^= (row&7).
  const f16* kg = k + (size_t)(bi*T_)*D_ + h*HD_;   // + s*512 + chunk*8
  const int sr8 = lane >> 3;          // 0..7 row-in-8
  const int sch = lane & 7;           // 16B chunk 0..7 within 128B row
  const int schs = (sch ^ sr8) << 3;  // pre-swizzled source col (f16)
  f16* kd0 = &Kb[(w*16)*64];
  f16* kd1 = &Kb[(w*16 + 8)*64];
  const int krd0 = (w*16 + l16)*64 + ((l4 ^ (l16 & 7)) << 3);
  const int krd1 = (w*16 + l16)*64 + (((l4 + 4) ^ (l16 & 7)) << 3);

  const int sbase = w*256;
  f32x4 acc[16];
  for (int c = 0; c < 16; ++c){
    gld16(kg + (size_t)(sbase + c*16 + sr8)*D_ + schs,     kd0);
    gld16(kg + (size_t)(sbase + c*16 + 8 + sr8)*D_ + schs, kd1);
    __syncthreads();
    f32x4 a = {0.f,0.f,0.f,0.f};
    a = MFMA16(ld8(&Kb[krd0]), q0, a, 0,0,0);
    a = MFMA16(ld8(&Kb[krd1]), q1, a, 0,0,0);
    const f16x4 bfrg = *reinterpret_cast<const f16x4*>(&Pb[l16*PSTR + sbase + c*16 + l4*4]);
#pragma unroll
    for (int j = 0; j < 4; ++j) a[j] += (float)bfrg[j];
    acc[c] = a;
    __syncthreads();
  }

  // ---- row max: in-lane + shfl + cross-wave ----
  float m = -3.4e38f;
#pragma unroll
  for (int c = 0; c < 16; ++c)
#pragma unroll
    for (int j = 0; j < 4; ++j) m = fmaxf(m, acc[c][j]);
  m = fmaxf(m, __shfl_xor(m, 16));
  m = fmaxf(m, __shfl_xor(m, 32));
  if (lane < 16) red[0][w][lane] = m;
  __syncthreads();
  m = fmaxf(fmaxf(red[0][0][l16], red[0][1][l16]),
            fmaxf(red[0][2][l16], red[0][3][l16]));

  // ---- exp2, accumulate l, pack unnormalized P to LDS ----
  float l = 0.f;
#pragma unroll
  for (int c = 0; c < 16; ++c){
    f16x4 pp;
#pragma unroll
    for (int j = 0; j < 4; ++j){
      const float e = exp2f(acc[c][j] - m);
      l += e;
      pp[j] = (f16)e;
    }
    *reinterpret_cast<f16x4*>(&Pb[l16*PSTR + sbase + c*16 + l4*4]) = pp;
  }
  l += __shfl_xor(l, 16);
  l += __shfl_xor(l, 32);
  if (lane < 16) red[1][w][lane] = l;

  // ---- PV with V staged through LDS in 8 chunks of 128 s ----
  // stage map: wave w stages d-rows [w*16,+16); 4 gld16/lane, 4 rows each.
  const f16* vg = vT + (size_t)bh*HD_*T_;
  const int vr4 = lane >> 4;                       // row-in-4
  const int vch = lane & 15;                       // 16B chunk 0..15 in 256B row
  f32x4 oo0 = {0.f,0.f,0.f,0.f}, oo1 = oo0, oo2 = oo0, oo3 = oo0;
#pragma unroll
  for (int sc0 = 0; sc0 < 8; ++sc0){
    __syncthreads();   // chunk sc0-1 reads done (first: P writes visible)
#pragma unroll
    for (int i = 0; i < 4; ++i){
      const int dl = w*16 + i*4 + vr4;
      gld16(vg + (size_t)dl*T_ + sc0*128 + ((vch ^ (dl & 7)) << 3),
            &Vb[(w*16 + i*4)*128]);
    }
    __syncthreads();
    const int prow = l16*PSTR + sc0*128 + l4*8;
    const int vrow = (w*16 + l16)*128;
    const int vsw  = l16 & 7;
    oo0 = MFMA16(*reinterpret_cast<const f16x8*>(&Pb[prow]),
                 ld8(&Vb[vrow + ((l4 ^ vsw) << 3)]), oo0, 0,0,0);
    oo1 = MFMA16(*reinterpret_cast<const f16x8*>(&Pb[prow + 32]),
                 ld8(&Vb[vrow + (((4 + l4) ^ vsw) << 3)]), oo1, 0,0,0);
    oo2 = MFMA16(*reinterpret_cast<const f16x8*>(&Pb[prow + 64]),
                 ld8(&Vb[vrow + (((8 + l4) ^ vsw) << 3)]), oo2, 0,0,0);
    oo3 = MFMA16(*reinterpret_cast<const f16x8*>(&Pb[prow + 96]),
                 ld8(&Vb[vrow + (((12 + l4) ^ vsw) << 3)]), oo3, 0,0,0);
  }
  const f32x4 o = (oo0 + oo1) + (oo2 + oo3);

#pragma unroll
  for (int j = 0; j < 4; ++j){
    const int row = l4*4 + j;
    const float lr = red[1][0][row] + red[1][1][row] + red[1][2][row] + red[1][3][row];
    const int t = t0 + row;
    X2[((size_t)(bi*T_ + t))*640 + h*HD_ + w*16 + l16] = (f16)(o[j]/lr);
  }

  // ---- edge gather: g[b,t,kk] += p_norm / H  (480 items, strided loop) ----
  for (int jj = tid; jj < 16*KN; jj += 256){
    const int r = jj/KN, kk = jj - r*KN;
    const float lr = red[1][0][r] + red[1][1][r] + red[1][2][r] + red[1][3][r];
    const int t = t0 + r;
    const int id = eidx[((size_t)(bi*T_ + t))*KN + kk];
    const float pv = (float)Pb[r*PSTR + id];
    atomicAdd(&gout[((size_t)(bi*T_ + t))*KN + kk], pv/lr*0.125f);
  }
}

// ---------------- edge: weighted neighbor-embedding mean -------------------
__global__ __launch_bounds__(128) void edge_kernel(
    const float* __restrict__ g, const float* __restrict__ E, f16* __restrict__ X2)
{
  __shared__ float gl[KN];
  __shared__ float ginv;
  const int bt = blockIdx.x;
  const int t = threadIdx.x;
  if (t < KN) gl[t] = g[(size_t)bt*KN + t];
  __syncthreads();
  if (t == 0){
    float s = 0.f;
#pragma unroll
    for (int i = 0; i < KN; ++i) s += gl[i];
    ginv = 1.0f/(s + 1e-6f);
  }
  __syncthreads();
  float acc = 0.f;
  const float* Ep = E + (size_t)bt*KN*ED_ + t;
#pragma unroll 5
  for (int kk = 0; kk < KN; ++kk) acc += gl[kk]*Ep[(size_t)kk*ED_];
  X2[(size_t)bt*640 + 512 + t] = (f16)(acc*ginv);
}

// ---------------- LayerNorm helpers ----------------------------------------
__device__ __forceinline__ float block_sum(float v, float* sbuf){
  for (int o = 32; o; o >>= 1) v += __shfl_down(v, o);
  __syncthreads();
  if ((threadIdx.x & 63) == 0) sbuf[threadIdx.x >> 6] = v;
  __syncthreads();
  return sbuf[0]+sbuf[1]+sbuf[2]+sbuf[3];
}

__global__ __launch_bounds__(256) void ln1_kernel(
    const float* __restrict__ hV, const float* __restrict__ hraw,
    const float* __restrict__ gn, const float* __restrict__ bn,
    float* __restrict__ hf, f16* __restrict__ hh)
{
  __shared__ float sbuf[4];
  const int r = blockIdx.x, t = threadIdx.x;
  const size_t base = (size_t)r*D_;
  float x0 = hV[base+t]     + hraw[base+t];
  float x1 = hV[base+t+256] + hraw[base+t+256];
  float s = block_sum(x0+x1, sbuf);
  const float mean = s*(1.f/512.f);
  float d0 = x0-mean, d1 = x1-mean;
  float vs = block_sum(d0*d0+d1*d1, sbuf);
  const float rstd = rsqrtf(vs*(1.f/512.f) + 1e-5f);
  float y0 = d0*rstd*gn[t]     + bn[t];
  float y1 = d1*rstd*gn[t+256] + bn[t+256];
  hf[base+t]     = y0;  hh[base+t]     = (f16)y0;
  hf[base+t+256] = y1;  hh[base+t+256] = (f16)y1;
}

__global__ __launch_bounds__(256) void final_kernel(
    const float* __restrict__ hf, const float* __restrict__ ffr,
    const float* __restrict__ gf, const float* __restrict__ bfv,
    const float* __restrict__ g2, const float* __restrict__ b2,
    float* __restrict__ out)
{
  __shared__ float sbuf[4];
  const int r = blockIdx.x, t = threadIdx.x;
  const size_t base = (size_t)r*D_;
  const float h0 = hf[base+t], h1 = hf[base+t+256];
  float x0 = h0 + ffr[base+t], x1 = h1 + ffr[base+t+256];
  float s = block_sum(x0+x1, sbuf);
  float mean = s*(1.f/512.f);
  float d0 = x0-mean, d1 = x1-mean;
  float vs = block_sum(d0*d0+d1*d1, sbuf);
  float rstd = rsqrtf(vs*(1.f/512.f) + 1e-6f);
  const float dh0 = d0*rstd*gf[t]     + bfv[t];
  const float dh1 = d1*rstd*gf[t+256] + bfv[t+256];
  const float y0 = h0 + dh0, y1 = h1 + dh1;
  s = block_sum(y0+y1, sbuf);
  mean = s*(1.f/512.f);
  d0 = y0-mean; d1 = y1-mean;
  vs = block_sum(d0*d0+d1*d1, sbuf);
  rstd = rsqrtf(vs*(1.f/512.f) + 1e-5f);
  out[base+t]     = d0*rstd*g2[t]     + b2[t];
  out[base+t+256] = d1*rstd*g2[t+256] + b2[t+256];
}

// ---------------------------------------------------------------------------
extern "C" void kernel_launch(void* const* d_in, const int* in_sizes, int n_in,
                              void* d_out, int out_size, void* d_ws, size_t ws_size,
                              hipStream_t stream)
{
  (void)in_sizes; (void)n_in; (void)out_size;
  const float* h_V  = (const float*)d_in[0];
  const float* kin  = (const float*)d_in[1];
  const float* vin  = (const float*)d_in[2];
  const float* E    = (const float*)d_in[3];
  const float* bias = (const float*)d_in[4];
  const float* Wq   = (const float*)d_in[5];
  const float* bq   = (const float*)d_in[6];
  const float* Wk   = (const float*)d_in[7];
  const float* bk   = (const float*)d_in[8];
  const float* Wv   = (const float*)d_in[9];
  const float* bv   = (const float*)d_in[10];
  const float* Wo   = (const float*)d_in[11];
  const float* bo   = (const float*)d_in[12];
  const float* tsc  = (const float*)d_in[13];
  const float* gn   = (const float*)d_in[14];
  const float* bn   = (const float*)d_in[15];
  const float* w1   = (const float*)d_in[16];
  const float* bw1  = (const float*)d_in[17];
  const float* w2   = (const float*)d_in[18];
  const float* bw2  = (const float*)d_in[19];
  const float* gf   = (const float*)d_in[20];
  const float* bfv  = (const float*)d_in[21];
  const float* g2   = (const float*)d_in[22];
  const float* b2   = (const float*)d_in[23];
  const int*   Eidx = (const int*)d_in[24];
  const int*   mask = (const int*)d_in[25];
  float* out = (float*)d_out;

  char* wsb = (char*)d_ws;
  size_t off = 0;
  auto alloc = [&](size_t bytes) -> void* {
    void* pp = wsb + off; off += (bytes + 255) & ~(size_t)255; return pp;
  };
  f16* hVb  = (f16*)alloc((size_t)M_*D_*2);
  f16* kbI  = (f16*)alloc((size_t)M_*D_*2);
  f16* vbI  = (f16*)alloc((size_t)M_*D_*2);
  f16* Wqb  = (f16*)alloc((size_t)D_*D_*2);
  f16* Wkb  = (f16*)alloc((size_t)D_*D_*2);
  f16* Wvb  = (f16*)alloc((size_t)D_*D_*2);
  f16* Wob  = (f16*)alloc((size_t)D_*(D_+ED_)*2);
  f16* w1b  = (f16*)alloc((size_t)DFF_*D_*2);
  f16* w2b  = (f16*)alloc((size_t)D_*DFF_*2);
  f16* qb   = (f16*)alloc((size_t)M_*D_*2);
  f16* kb   = (f16*)alloc((size_t)M_*D_*2);
  f16* vT   = (f16*)alloc((size_t)M_*D_*2);
  f16* biasP= (f16*)alloc((size_t)B_*T_*T_*2);
  f16* X2   = (f16*)alloc((size_t)M_*640*2);
  float* gbuf = (float*)alloc((size_t)M_*KN*4);
  float* hraw = (float*)alloc((size_t)M_*D_*4);   // reused as ffraw
  float* hf   = (float*)alloc((size_t)M_*D_*4);
  f16*   hh   = (f16*)alloc((size_t)M_*D_*2);
  f16*   ff1  = (f16*)alloc((size_t)M_*DFF_*2);
  if (ws_size < off) return;  // scratch insufficient -> loud validation failure
  float* ffraw = hraw;

  // 1) converts fp32 -> f16 (one launch) + bias prep (fused g-zero)
  {
    CvtJobs J;
    const float* srcs[9] = {h_V, kin, vin, Wq, Wk, Wv, Wo, w1, w2};
    f16* dsts[9] = {hVb, kbI, vbI, Wqb, Wkb, Wvb, Wob, w1b, w2b};
    const int n4s[9] = {M_*D_/4, M_*D_/4, M_*D_/4, D_*D_/4, D_*D_/4, D_*D_/4,
                        D_*(D_+ED_)/4, DFF_*D_/4, D_*DFF_/4};
    int cum = 0;
    for (int i = 0; i < 9; ++i){
      J.s[i] = srcs[i]; J.d[i] = dsts[i]; J.start[i] = cum;
      cum += n4s[i]/256;
    }
    J.start[9] = cum;
    cvt9_kernel<<<cum,256,0,stream>>>(J);
  }
  biasprep_kernel<<<B_*T_*T_/8/256,256,0,stream>>>(bias, mask, tsc, biasP, gbuf);

  // 2) batched q/k/v projections (q pre-scaled for exp2 softmax; v -> vT)
  qkv_tile<<<384,256,0,stream>>>(hVb, kbI, vbI, Wqb, Wkb, Wvb, bq, bk, bv, tsc, qb, kb, vT);

  // 3) fused attention (QK^T + softmax + PV + edge gather)
  attn_fused<<<2048,256,0,stream>>>(qb, kb, vT, biasP, Eidx, X2, gbuf);

  // 4) edge embedding
  edge_kernel<<<M_,128,0,stream>>>(gbuf, E, X2);

  // 5) out-proj (128x64 tiles, 256 blocks) + residual LN
  gemm_n64<2><<<256,256,0,stream>>>(X2, Wob, bo, hraw, D_+ED_, D_, 8);
  ln1_kernel<<<M_,256,0,stream>>>(h_V, hraw, gn, bn, hf, hh);

  // 6) FFN: FF1 128x128 (512 blocks), FF2 128x64 (256 blocks)
  gemm_tile<1><<<512,256,0,stream>>>(hh, w1b, bw1, ff1, D_, DFF_, 16);
  gemm_n64<2><<<256,256,0,stream>>>(ff1, w2b, bw2, ffraw, DFF_, D_, 8);

  // 7) final double-LN
  final_kernel<<<M_,256,0,stream>>>(hf, ffraw, gf, bfv, g2, b2, out);
}

// Round 9
// 186.267 us; speedup vs baseline: 2.2537x; 1.0933x over previous
//
#include <hip/hip_runtime.h>
#include <hip/hip_fp16.h>
#include <math.h>

#define B_ 4
#define T_ 1024
#define D_ 512
#define H_ 8
#define HD_ 64
#define KN 30
#define ED_ 128
#define DFF_ 2048
#define M_ 4096   // B*T
#define BH_ 32

typedef _Float16 f16;
typedef __attribute__((ext_vector_type(8))) _Float16 f16x8;
typedef __attribute__((ext_vector_type(4))) _Float16 f16x4;
typedef __attribute__((ext_vector_type(4))) float f32x4;

#define MFMA16 __builtin_amdgcn_mfma_f32_16x16x32_f16
#define LOG2E 1.44269504088896f

__device__ __forceinline__ f16x8 ld8(const f16* p){ return *reinterpret_cast<const f16x8*>(p); }

__device__ __forceinline__ void gld16(const void* g, void* l){
  __builtin_amdgcn_global_load_lds((const __attribute__((address_space(1))) void*)g,
                                   (__attribute__((address_space(3))) void*)l, 16, 0, 0);
}

// ---------------- combined fp32 -> fp16 convert (9 tensors, 1 launch) -------
struct CvtJobs {
  const float* s[9];
  f16* d[9];
  int start[10];   // cumulative block starts; each block = 256 float4s
};

__global__ __launch_bounds__(256) void cvt9_kernel(CvtJobs J){
  const int blk = blockIdx.x;
  int j = 0;
  while (j < 8 && blk >= J.start[j+1]) ++j;
  const int i = (blk - J.start[j])*256 + threadIdx.x;
  float4 v = reinterpret_cast<const float4*>(J.s[j])[i];
  union { f16 h[4]; ushort4 u; } o;
  o.h[0]=(f16)v.x; o.h[1]=(f16)v.y; o.h[2]=(f16)v.z; o.h[3]=(f16)v.w;
  reinterpret_cast<ushort4*>(J.d[j])[i] = o.u;
}

// ---------------- bias prep: f16((bias + mask*-6e4) * rtemp * log2e) --------
// blocks 0..479 also zero the 122880-float g buffer (fused zero_kernel).
__global__ __launch_bounds__(256) void biasprep_kernel(
    const float* __restrict__ bias, const int* __restrict__ mask,
    const float* __restrict__ tsc, f16* __restrict__ biasP,
    float* __restrict__ gzero)
{
  const int gid = blockIdx.x*256 + threadIdx.x;      // 524288 threads, 8 elems each
  if (blockIdx.x < (M_*KN)/256) gzero[gid] = 0.f;
  const float s = exp2f(-2.0f*tanhf(tsc[0]))*LOG2E;  // log2e / 4^tanh(t)
  const int b = gid >> 17;                            // T*T/8 = 131072 per batch
  const int rem = gid & 131071;
  const int idx8 = rem*8;
  const int s0 = idx8 & 1023;
  const size_t gbase = (size_t)b*T_*T_ + idx8;
  float4 v0 = *reinterpret_cast<const float4*>(bias + gbase);
  float4 v1 = *reinterpret_cast<const float4*>(bias + gbase + 4);
  int4 m0 = *reinterpret_cast<const int4*>(mask + b*T_ + s0);
  int4 m1 = *reinterpret_cast<const int4*>(mask + b*T_ + s0 + 4);
  float x[8] = {v0.x,v0.y,v0.z,v0.w,v1.x,v1.y,v1.z,v1.w};
  int  mm[8] = {m0.x,m0.y,m0.z,m0.w,m1.x,m1.y,m1.z,m1.w};
  union { f16 h[8]; ushort4 u[2]; } o;
#pragma unroll
  for (int i = 0; i < 8; ++i){
    float t = (x[i] + (mm[i] ? 0.f : -60000.f))*s;
    o.h[i] = (f16)fmaxf(t, -60000.f);
  }
  reinterpret_cast<ushort4*>(biasP + gbase)[0] = o.u[0];
  reinterpret_cast<ushort4*>(biasP + gbase)[1] = o.u[1];
}

// =============== staged MFMA GEMM (m97 structure): C = X @ W.T ==============
// 128x128 tile. EPI 1: f16 gelu(acc+bias). EPI 2: f32 acc+bias.
template<int EPI>
__global__ __launch_bounds__(256,2) void gemm_tile(
    const f16* __restrict__ X, const f16* __restrict__ W,
    const float* __restrict__ bias, void* __restrict__ outp,
    int Kd, int ldo, int nbN)
{
  __shared__ f16 As[128*32];
  __shared__ f16 Bs[128*32];
  const int nwg = gridDim.x;
  const int bid = blockIdx.x;
  const int swz = (bid & 7)*(nwg >> 3) + (bid >> 3);
  const int mb = swz / nbN, nb = swz - mb*nbN;
  const int rb = mb*128, cb = nb*128;
  const int tid = threadIdx.x;
  const int w = tid >> 6, lane = tid & 63;
  const int l16 = lane & 15, l4 = lane >> 4;
  const int wr = w >> 1, wc = w & 1;
  const int sr = lane >> 2, sc = (lane & 3)*8;
  const f16* Ax0 = X + (size_t)(rb + w*16 + sr)*Kd + sc;
  const f16* Ax1 = X + (size_t)(rb + 64 + w*16 + sr)*Kd + sc;
  const f16* Bx0 = W + (size_t)(cb + w*16 + sr)*Kd + sc;
  const f16* Bx1 = W + (size_t)(cb + 64 + w*16 + sr)*Kd + sc;
  f16* Ad0 = &As[(w*16)*32];
  f16* Ad1 = &As[(64 + w*16)*32];
  f16* Bd0 = &Bs[(w*16)*32];
  f16* Bd1 = &Bs[(64 + w*16)*32];

  f32x4 acc[4][4];
#pragma unroll
  for (int m = 0; m < 4; ++m)
#pragma unroll
    for (int n = 0; n < 4; ++n) acc[m][n] = (f32x4){0.f,0.f,0.f,0.f};

  for (int k0 = 0; k0 < Kd; k0 += 32){
    gld16(Ax0 + k0, Ad0);
    gld16(Ax1 + k0, Ad1);
    gld16(Bx0 + k0, Bd0);
    gld16(Bx1 + k0, Bd1);
    __syncthreads();
    f16x8 a[4], b[4];
#pragma unroll
    for (int m = 0; m < 4; ++m) a[m] = ld8(&As[(wr*64 + m*16 + l16)*32 + l4*8]);
#pragma unroll
    for (int n = 0; n < 4; ++n) b[n] = ld8(&Bs[(wc*64 + n*16 + l16)*32 + l4*8]);
#pragma unroll
    for (int m = 0; m < 4; ++m)
#pragma unroll
      for (int n = 0; n < 4; ++n)
        acc[m][n] = MFMA16(a[m], b[n], acc[m][n], 0,0,0);
    __syncthreads();
  }

#pragma unroll
  for (int n = 0; n < 4; ++n){
    const int col = cb + wc*64 + n*16 + l16;
    const float bv = bias[col];
#pragma unroll
    for (int m = 0; m < 4; ++m){
#pragma unroll
      for (int j = 0; j < 4; ++j){
        const int row = rb + wr*64 + m*16 + l4*4 + j;
        float v = acc[m][n][j] + bv;
        if (EPI == 1){
          v = 0.5f*v*(1.0f + erff(v*0.70710678118654752f));
          ((f16*)outp)[(size_t)row*ldo + col] = (f16)v;
        } else {
          ((float*)outp)[(size_t)row*ldo + col] = v;
        }
      }
    }
  }
}

// =============== 128x64-tile GEMM (2x CU coverage for N=512 outputs) ========
template<int EPI>
__global__ __launch_bounds__(256,2) void gemm_n64(
    const f16* __restrict__ X, const f16* __restrict__ W,
    const float* __restrict__ bias, void* __restrict__ outp,
    int Kd, int ldo, int nbN)
{
  __shared__ f16 As[128*32];
  __shared__ f16 Bs[64*32];
  const int nwg = gridDim.x;
  const int bid = blockIdx.x;
  const int swz = (bid & 7)*(nwg >> 3) + (bid >> 3);
  const int mb = swz / nbN, nb = swz - mb*nbN;
  const int rb = mb*128, cb = nb*64;
  const int tid = threadIdx.x;
  const int w = tid >> 6, lane = tid & 63;
  const int l16 = lane & 15, l4 = lane >> 4;
  const int wr = w >> 1, wc = w & 1;
  const int sr = lane >> 2, sc = (lane & 3)*8;
  const f16* Ax0 = X + (size_t)(rb + w*16 + sr)*Kd + sc;
  const f16* Ax1 = X + (size_t)(rb + 64 + w*16 + sr)*Kd + sc;
  const f16* Bx0 = W + (size_t)(cb + w*16 + sr)*Kd + sc;
  f16* Ad0 = &As[(w*16)*32];
  f16* Ad1 = &As[(64 + w*16)*32];
  f16* Bd0 = &Bs[(w*16)*32];

  f32x4 acc[4][2];
#pragma unroll
  for (int m = 0; m < 4; ++m)
#pragma unroll
    for (int n = 0; n < 2; ++n) acc[m][n] = (f32x4){0.f,0.f,0.f,0.f};

  for (int k0 = 0; k0 < Kd; k0 += 32){
    gld16(Ax0 + k0, Ad0);
    gld16(Ax1 + k0, Ad1);
    gld16(Bx0 + k0, Bd0);
    __syncthreads();
    f16x8 a[4], b[2];
#pragma unroll
    for (int m = 0; m < 4; ++m) a[m] = ld8(&As[(wr*64 + m*16 + l16)*32 + l4*8]);
#pragma unroll
    for (int n = 0; n < 2; ++n) b[n] = ld8(&Bs[(wc*32 + n*16 + l16)*32 + l4*8]);
#pragma unroll
    for (int m = 0; m < 4; ++m)
#pragma unroll
      for (int n = 0; n < 2; ++n)
        acc[m][n] = MFMA16(a[m], b[n], acc[m][n], 0,0,0);
    __syncthreads();
  }

#pragma unroll
  for (int n = 0; n < 2; ++n){
    const int col = cb + wc*32 + n*16 + l16;
    const float bv = bias[col];
#pragma unroll
    for (int m = 0; m < 4; ++m){
#pragma unroll
      for (int j = 0; j < 4; ++j){
        const int row = rb + wr*64 + m*16 + l4*4 + j;
        float v = acc[m][n][j] + bv;
        if (EPI == 1){
          v = 0.5f*v*(1.0f + erff(v*0.70710678118654752f));
          ((f16*)outp)[(size_t)row*ldo + col] = (f16)v;
        } else {
          ((float*)outp)[(size_t)row*ldo + col] = v;
        }
      }
    }
  }
}

// =============== batched QKV projection (one launch, 3 GEMMs) ===============
__global__ __launch_bounds__(256,2) void qkv_tile(
    const f16* __restrict__ hV, const f16* __restrict__ kI, const f16* __restrict__ vI,
    const f16* __restrict__ Wq, const f16* __restrict__ Wk, const f16* __restrict__ Wv,
    const float* __restrict__ bq, const float* __restrict__ bk, const float* __restrict__ bv,
    const float* __restrict__ tsc,
    f16* __restrict__ qo, f16* __restrict__ ko, f16* __restrict__ vT)
{
  __shared__ f16 As[128*32];
  __shared__ f16 Bs[128*32];
  const int bid = blockIdx.x;
  const int swz = (bid & 7)*48 + (bid >> 3);
  const int g = swz >> 7;
  const int r = swz & 127;
  const int mb = r >> 2, nb = r & 3;
  const f16* X  = (g == 0) ? hV : ((g == 1) ? kI : vI);
  const f16* W  = (g == 0) ? Wq : ((g == 1) ? Wk : Wv);
  const float* bias = (g == 0) ? bq : ((g == 1) ? bk : bv);
  const int rb = mb*128, cb = nb*128;
  const int tid = threadIdx.x;
  const int w = tid >> 6, lane = tid & 63;
  const int l16 = lane & 15, l4 = lane >> 4;
  const int wr = w >> 1, wc = w & 1;
  const int sr = lane >> 2, sc = (lane & 3)*8;
  const f16* Ax0 = X + (size_t)(rb + w*16 + sr)*D_ + sc;
  const f16* Ax1 = X + (size_t)(rb + 64 + w*16 + sr)*D_ + sc;
  const f16* Bx0 = W + (size_t)(cb + w*16 + sr)*D_ + sc;
  const f16* Bx1 = W + (size_t)(cb + 64 + w*16 + sr)*D_ + sc;
  f16* Ad0 = &As[(w*16)*32];
  f16* Ad1 = &As[(64 + w*16)*32];
  f16* Bd0 = &Bs[(w*16)*32];
  f16* Bd1 = &Bs[(64 + w*16)*32];

  f32x4 acc[4][4];
#pragma unroll
  for (int m = 0; m < 4; ++m)
#pragma unroll
    for (int n = 0; n < 4; ++n) acc[m][n] = (f32x4){0.f,0.f,0.f,0.f};

  for (int k0 = 0; k0 < D_; k0 += 32){
    gld16(Ax0 + k0, Ad0);
    gld16(Ax1 + k0, Ad1);
    gld16(Bx0 + k0, Bd0);
    gld16(Bx1 + k0, Bd1);
    __syncthreads();
    f16x8 a[4], b[4];
#pragma unroll
    for (int m = 0; m < 4; ++m) a[m] = ld8(&As[(wr*64 + m*16 + l16)*32 + l4*8]);
#pragma unroll
    for (int n = 0; n < 4; ++n) b[n] = ld8(&Bs[(wc*64 + n*16 + l16)*32 + l4*8]);
#pragma unroll
    for (int m = 0; m < 4; ++m)
#pragma unroll
      for (int n = 0; n < 4; ++n)
        acc[m][n] = MFMA16(a[m], b[n], acc[m][n], 0,0,0);
    __syncthreads();
  }

  const float qs = exp2f(-2.0f*tanhf(tsc[0]))*LOG2E*0.125f;
  const float scale = (g == 0) ? qs : 1.0f;
  f16* out = (g == 0) ? qo : ko;
#pragma unroll
  for (int n = 0; n < 4; ++n){
    const int col = cb + wc*64 + n*16 + l16;
    const float bv = bias[col];
#pragma unroll
    for (int m = 0; m < 4; ++m){
#pragma unroll
      for (int j = 0; j < 4; ++j){
        const int row = rb + wr*64 + m*16 + l4*4 + j;
        const float v = (acc[m][n][j] + bv)*scale;
        if (g < 2){
          out[(size_t)row*D_ + col] = (f16)v;
        } else {
          const int b = row >> 10, t = row & (T_-1);
          const int h = col >> 6,  dl = col & (HD_-1);
          vT[(((size_t)b*H_ + h)*HD_ + dl)*T_ + t] = (f16)v;
        }
      }
    }
  }
}

// =============== fused attention (chunked, low-LDS, 4 blocks/CU) ============
// block = 16 q-rows x one (b,h); 4 waves. s processed in 8 chunks of 128:
// QK phase: cooperative 16KB K-chunk stage + 4KB bias-chunk stage -> 4 MFMA/wave
// (wave w owns s-local [w*32,+32)). Scores live in acc[16] registers.
// Softmax in-register. PV phase: per chunk, waves write their P slice (4KB)
// + cooperative 16KB V-chunk stage -> 4 MFMA/wave; edge-gather per chunk.
// All LDS chunk buffers XOR-swizzled (16B chunk ^= row&7, pre-swizzled global
// source since global_load_lds writes linearly).
__global__ __launch_bounds__(256,4) void attn_fused(
    const f16* __restrict__ q, const f16* __restrict__ k, const f16* __restrict__ vT,
    const f16* __restrict__ biasP, const int* __restrict__ eidx,
    f16* __restrict__ X2, float* __restrict__ gout)
{
  __shared__ f16 Sb[8192];        // 16 KB: K chunk [128 s][64 d] / V chunk [64 d][128 s]
  __shared__ f16 Pc[16*128];      // 4 KB: bias chunk / P chunk [16 q][128 s]
  __shared__ float red[2][4][16];
  const int bid = blockIdx.x;
  const int swz = (bid & 7)*256 + (bid >> 3);   // XCD gets 4 contiguous bh
  const int bh = swz >> 6, tb = swz & 63;
  const int bi = bh >> 3, h = bh & 7;
  const int t0 = tb*16;
  const int tid = threadIdx.x, w = tid >> 6, lane = tid & 63;
  const int l16 = lane & 15, l4 = lane >> 4;
  const int key = l16 & 7;        // XOR-swizzle key for frag reads

  // ---- Q fragments + gather tuples (registers, loaded once) ----
  const f16* qp = q + (size_t)(bi*T_ + t0 + l16)*D_ + h*HD_ + l4*8;
  const f16x8 q0 = ld8(qp), q1 = ld8(qp + 32);
  int g_id0, g_r0, g_kk0, g_id1 = -1, g_r1 = 0, g_kk1 = 0;
  g_r0 = tid/KN; g_kk0 = tid - g_r0*KN;
  g_id0 = eidx[((size_t)(bi*T_ + t0 + g_r0))*KN + g_kk0];
  if (tid + 256 < 16*KN){
    g_r1 = (tid+256)/KN; g_kk1 = (tid+256) - g_r1*KN;
    g_id1 = eidx[((size_t)(bi*T_ + t0 + g_r1))*KN + g_kk1];
  }

  const f16* kg = k + (size_t)(bi*T_)*D_ + h*HD_;
  const f16* bg = biasP + ((size_t)(bi*T_ + t0))*T_;
  const f16* vg = vT + (size_t)bh*HD_*T_;

  // ---- QK^T: 8 chunks of 128 s ----
  f32x4 acc[16];
#pragma unroll
  for (int c = 0; c < 8; ++c){
    if (c) __syncthreads();                       // prev chunk's LDS reads done
    // stage K chunk: 1024x16B; rows 128B = 8 chunks, src col pre-swizzled
#pragma unroll
    for (int i = 0; i < 4; ++i){
      const int cidx = i*256 + w*64 + lane;
      const int r = cidx >> 3, p = cidx & 7;
      gld16(kg + (size_t)(c*128 + r)*D_ + ((p ^ (r & 7)) << 3),
            &Sb[(i*256 + w*64)*8]);
    }
    // stage bias chunk: 256x16B; rows 256B = 16 chunks
    {
      const int cidx = w*64 + lane;
      const int r = cidx >> 4, p = cidx & 15;
      gld16(bg + (size_t)r*T_ + c*128 + ((p ^ (r & 7)) << 3),
            &Pc[w*512]);
    }
    __syncthreads();                              // stage visible
#pragma unroll
    for (int step = 0; step < 2; ++step){
      const int r = w*32 + step*16 + l16;         // local s row (r&7 == key)
      f32x4 a = {0.f,0.f,0.f,0.f};
      a = MFMA16(ld8(&Sb[r*64 + ((l4 ^ key) << 3)]),       q0, a, 0,0,0);
      a = MFMA16(ld8(&Sb[r*64 + (((4 + l4) ^ key) << 3)]), q1, a, 0,0,0);
      const int slb = w*32 + step*16 + l4*4;
      const f16x4 bf = *reinterpret_cast<const f16x4*>(
          &Pc[l16*128 + (((slb >> 3) ^ key) << 3) + (slb & 7)]);
#pragma unroll
      for (int j = 0; j < 4; ++j) a[j] += (float)bf[j];
      acc[c*2 + step] = a;
    }
  }

  // ---- softmax: in-lane 64 values + shfl + cross-wave ----
  float m = -3.4e38f;
#pragma unroll
  for (int c = 0; c < 16; ++c)
#pragma unroll
    for (int j = 0; j < 4; ++j) m = fmaxf(m, acc[c][j]);
  m = fmaxf(m, __shfl_xor(m, 16));
  m = fmaxf(m, __shfl_xor(m, 32));
  if (lane < 16) red[0][w][lane] = m;
  __syncthreads();
  m = fmaxf(fmaxf(red[0][0][l16], red[0][1][l16]),
            fmaxf(red[0][2][l16], red[0][3][l16]));
  float l = 0.f;
#pragma unroll
  for (int c = 0; c < 16; ++c)
#pragma unroll
    for (int j = 0; j < 4; ++j){
      const float e = exp2f(acc[c][j] - m);
      l += e;
      acc[c][j] = e;                               // acc now holds unnormalized P
    }
  l += __shfl_xor(l, 16);
  l += __shfl_xor(l, 32);
  if (lane < 16) red[1][w][lane] = l;

  // ---- PV: 8 chunks of 128 s; P from regs -> Pc, V staged -> Sb ----
  f32x4 oo0 = {0.f,0.f,0.f,0.f}, oo1 = oo0, oo2 = oo0, oo3 = oo0;
#pragma unroll
  for (int sc = 0; sc < 8; ++sc){
    __syncthreads();                              // prev reads done (+red[1] for sc=0)
    // write this wave's P slice (s-local [w*32,+32))
#pragma unroll
    for (int step = 0; step < 2; ++step){
      const int slb = w*32 + step*16 + l4*4;
      f16x4 pp;
#pragma unroll
      for (int j = 0; j < 4; ++j) pp[j] = (f16)acc[sc*2 + step][j];
      *reinterpret_cast<f16x4*>(
          &Pc[l16*128 + (((slb >> 3) ^ key) << 3) + (slb & 7)]) = pp;
    }
    // stage V chunk: 1024x16B; rows 256B = 16 chunks
#pragma unroll
    for (int i = 0; i < 4; ++i){
      const int cidx = i*256 + w*64 + lane;
      const int r = cidx >> 4, p = cidx & 15;
      gld16(vg + (size_t)r*T_ + sc*128 + ((p ^ (r & 7)) << 3),
            &Sb[(i*256 + w*64)*8]);
    }
    __syncthreads();                              // P + V visible
    const int vrow = (w*16 + l16)*128;
#pragma unroll
    for (int grp = 0; grp < 4; ++grp){
      const int ch = (grp*4 + l4) ^ key;
      const f16x8 pa = ld8(&Pc[l16*128 + (ch << 3)]);
      const f16x8 vb = ld8(&Sb[vrow + (ch << 3)]);
      if (grp == 0)      oo0 = MFMA16(pa, vb, oo0, 0,0,0);
      else if (grp == 1) oo1 = MFMA16(pa, vb, oo1, 0,0,0);
      else if (grp == 2) oo2 = MFMA16(pa, vb, oo2, 0,0,0);
      else               oo3 = MFMA16(pa, vb, oo3, 0,0,0);
    }
    // edge gather for ids in this s-chunk
    if ((g_id0 >> 7) == sc){
      const float lr = red[1][0][g_r0] + red[1][1][g_r0] + red[1][2][g_r0] + red[1][3][g_r0];
      const int sl = g_id0 & 127;
      const float pv = (float)Pc[g_r0*128 + ((((sl >> 3) ^ (g_r0 & 7)) << 3) | (sl & 7))];
      atomicAdd(&gout[((size_t)(bi*T_ + t0 + g_r0))*KN + g_kk0], pv/lr*0.125f);
    }
    if (g_id1 >= 0 && (g_id1 >> 7) == sc){
      const float lr = red[1][0][g_r1] + red[1][1][g_r1] + red[1][2][g_r1] + red[1][3][g_r1];
      const int sl = g_id1 & 127;
      const float pv = (float)Pc[g_r1*128 + ((((sl >> 3) ^ (g_r1 & 7)) << 3) | (sl & 7))];
      atomicAdd(&gout[((size_t)(bi*T_ + t0 + g_r1))*KN + g_kk1], pv/lr*0.125f);
    }
  }
  const f32x4 o = (oo0 + oo1) + (oo2 + oo3);

#pragma unroll
  for (int j = 0; j < 4; ++j){
    const int row = l4*4 + j;
    const float lr = red[1][0][row] + red[1][1][row] + red[1][2][row] + red[1][3][row];
    const int t = t0 + row;
    X2[((size_t)(bi*T_ + t))*640 + h*HD_ + w*16 + l16] = (f16)(o[j]/lr);
  }
}

// ---------------- edge: weighted neighbor-embedding mean -------------------
__global__ __launch_bounds__(128) void edge_kernel(
    const float* __restrict__ g, const float* __restrict__ E, f16* __restrict__ X2)
{
  __shared__ float gl[KN];
  __shared__ float ginv;
  const int bt = blockIdx.x;
  const int t = threadIdx.x;
  if (t < KN) gl[t] = g[(size_t)bt*KN + t];
  __syncthreads();
  if (t == 0){
    float s = 0.f;
#pragma unroll
    for (int i = 0; i < KN; ++i) s += gl[i];
    ginv = 1.0f/(s + 1e-6f);
  }
  __syncthreads();
  float acc = 0.f;
  const float* Ep = E + (size_t)bt*KN*ED_ + t;
#pragma unroll 5
  for (int kk = 0; kk < KN; ++kk) acc += gl[kk]*Ep[(size_t)kk*ED_];
  X2[(size_t)bt*640 + 512 + t] = (f16)(acc*ginv);
}

// ---------------- LayerNorm helpers ----------------------------------------
__device__ __forceinline__ float block_sum(float v, float* sbuf){
  for (int o = 32; o; o >>= 1) v += __shfl_down(v, o);
  __syncthreads();
  if ((threadIdx.x & 63) == 0) sbuf[threadIdx.x >> 6] = v;
  __syncthreads();
  return sbuf[0]+sbuf[1]+sbuf[2]+sbuf[3];
}

__global__ __launch_bounds__(256) void ln1_kernel(
    const float* __restrict__ hV, const float* __restrict__ hraw,
    const float* __restrict__ gn, const float* __restrict__ bn,
    float* __restrict__ hf, f16* __restrict__ hh)
{
  __shared__ float sbuf[4];
  const int r = blockIdx.x, t = threadIdx.x;
  const size_t base = (size_t)r*D_;
  float x0 = hV[base+t]     + hraw[base+t];
  float x1 = hV[base+t+256] + hraw[base+t+256];
  float s = block_sum(x0+x1, sbuf);
  const float mean = s*(1.f/512.f);
  float d0 = x0-mean, d1 = x1-mean;
  float vs = block_sum(d0*d0+d1*d1, sbuf);
  const float rstd = rsqrtf(vs*(1.f/512.f) + 1e-5f);
  float y0 = d0*rstd*gn[t]     + bn[t];
  float y1 = d1*rstd*gn[t+256] + bn[t+256];
  hf[base+t]     = y0;  hh[base+t]     = (f16)y0;
  hf[base+t+256] = y1;  hh[base+t+256] = (f16)y1;
}

__global__ __launch_bounds__(256) void final_kernel(
    const float* __restrict__ hf, const float* __restrict__ ffr,
    const float* __restrict__ gf, const float* __restrict__ bfv,
    const float* __restrict__ g2, const float* __restrict__ b2,
    float* __restrict__ out)
{
  __shared__ float sbuf[4];
  const int r = blockIdx.x, t = threadIdx.x;
  const size_t base = (size_t)r*D_;
  const float h0 = hf[base+t], h1 = hf[base+t+256];
  float x0 = h0 + ffr[base+t], x1 = h1 + ffr[base+t+256];
  float s = block_sum(x0+x1, sbuf);
  float mean = s*(1.f/512.f);
  float d0 = x0-mean, d1 = x1-mean;
  float vs = block_sum(d0*d0+d1*d1, sbuf);
  float rstd = rsqrtf(vs*(1.f/512.f) + 1e-6f);
  const float dh0 = d0*rstd*gf[t]     + bfv[t];
  const float dh1 = d1*rstd*gf[t+256] + bfv[t+256];
  const float y0 = h0 + dh0, y1 = h1 + dh1;
  s = block_sum(y0+y1, sbuf);
  mean = s*(1.f/512.f);
  d0 = y0-mean; d1 = y1-mean;
  vs = block_sum(d0*d0+d1*d1, sbuf);
  rstd = rsqrtf(vs*(1.f/512.f) + 1e-5f);
  out[base+t]     = d0*rstd*g2[t]     + b2[t];
  out[base+t+256] = d1*rstd*g2[t+256] + b2[t+256];
}

// ---------------------------------------------------------------------------
extern "C" void kernel_launch(void* const* d_in, const int* in_sizes, int n_in,
                              void* d_out, int out_size, void* d_ws, size_t ws_size,
                              hipStream_t stream)
{
  (void)in_sizes; (void)n_in; (void)out_size;
  const float* h_V  = (const float*)d_in[0];
  const float* kin  = (const float*)d_in[1];
  const float* vin  = (const float*)d_in[2];
  const float* E    = (const float*)d_in[3];
  const float* bias = (const float*)d_in[4];
  const float* Wq   = (const float*)d_in[5];
  const float* bq   = (const float*)d_in[6];
  const float* Wk   = (const float*)d_in[7];
  const float* bk   = (const float*)d_in[8];
  const float* Wv   = (const float*)d_in[9];
  const float* bv   = (const float*)d_in[10];
  const float* Wo   = (const float*)d_in[11];
  const float* bo   = (const float*)d_in[12];
  const float* tsc  = (const float*)d_in[13];
  const float* gn   = (const float*)d_in[14];
  const float* bn   = (const float*)d_in[15];
  const float* w1   = (const float*)d_in[16];
  const float* bw1  = (const float*)d_in[17];
  const float* w2   = (const float*)d_in[18];
  const float* bw2  = (const float*)d_in[19];
  const float* gf   = (const float*)d_in[20];
  const float* bfv  = (const float*)d_in[21];
  const float* g2   = (const float*)d_in[22];
  const float* b2   = (const float*)d_in[23];
  const int*   Eidx = (const int*)d_in[24];
  const int*   mask = (const int*)d_in[25];
  float* out = (float*)d_out;

  char* wsb = (char*)d_ws;
  size_t off = 0;
  auto alloc = [&](size_t bytes) -> void* {
    void* pp = wsb + off; off += (bytes + 255) & ~(size_t)255; return pp;
  };
  f16* hVb  = (f16*)alloc((size_t)M_*D_*2);
  f16* kbI  = (f16*)alloc((size_t)M_*D_*2);
  f16* vbI  = (f16*)alloc((size_t)M_*D_*2);
  f16* Wqb  = (f16*)alloc((size_t)D_*D_*2);
  f16* Wkb  = (f16*)alloc((size_t)D_*D_*2);
  f16* Wvb  = (f16*)alloc((size_t)D_*D_*2);
  f16* Wob  = (f16*)alloc((size_t)D_*(D_+ED_)*2);
  f16* w1b  = (f16*)alloc((size_t)DFF_*D_*2);
  f16* w2b  = (f16*)alloc((size_t)D_*DFF_*2);
  f16* qb   = (f16*)alloc((size_t)M_*D_*2);
  f16* kb   = (f16*)alloc((size_t)M_*D_*2);
  f16* vT   = (f16*)alloc((size_t)M_*D_*2);
  f16* biasP= (f16*)alloc((size_t)B_*T_*T_*2);
  f16* X2   = (f16*)alloc((size_t)M_*640*2);
  float* gbuf = (float*)alloc((size_t)M_*KN*4);
  float* hraw = (float*)alloc((size_t)M_*D_*4);   // reused as ffraw
  float* hf   = (float*)alloc((size_t)M_*D_*4);
  f16*   hh   = (f16*)alloc((size_t)M_*D_*2);
  f16*   ff1  = (f16*)alloc((size_t)M_*DFF_*2);
  if (ws_size < off) return;  // scratch insufficient -> loud validation failure
  float* ffraw = hraw;

  // 1) converts fp32 -> f16 (one launch) + bias prep (fused g-zero)
  {
    CvtJobs J;
    const float* srcs[9] = {h_V, kin, vin, Wq, Wk, Wv, Wo, w1, w2};
    f16* dsts[9] = {hVb, kbI, vbI, Wqb, Wkb, Wvb, Wob, w1b, w2b};
    const int n4s[9] = {M_*D_/4, M_*D_/4, M_*D_/4, D_*D_/4, D_*D_/4, D_*D_/4,
                        D_*(D_+ED_)/4, DFF_*D_/4, D_*DFF_/4};
    int cum = 0;
    for (int i = 0; i < 9; ++i){
      J.s[i] = srcs[i]; J.d[i] = dsts[i]; J.start[i] = cum;
      cum += n4s[i]/256;
    }
    J.start[9] = cum;
    cvt9_kernel<<<cum,256,0,stream>>>(J);
  }
  biasprep_kernel<<<B_*T_*T_/8/256,256,0,stream>>>(bias, mask, tsc, biasP, gbuf);

  // 2) batched q/k/v projections (q pre-scaled for exp2 softmax; v -> vT)
  qkv_tile<<<384,256,0,stream>>>(hVb, kbI, vbI, Wqb, Wkb, Wvb, bq, bk, bv, tsc, qb, kb, vT);

  // 3) fused attention (QK^T + softmax + PV + edge gather)
  attn_fused<<<2048,256,0,stream>>>(qb, kb, vT, biasP, Eidx, X2, gbuf);

  // 4) edge embedding
  edge_kernel<<<M_,128,0,stream>>>(gbuf, E, X2);

  // 5) out-proj (128x64 tiles, 256 blocks) + residual LN
  gemm_n64<2><<<256,256,0,stream>>>(X2, Wob, bo, hraw, D_+ED_, D_, 8);
  ln1_kernel<<<M_,256,0,stream>>>(h_V, hraw, gn, bn, hf, hh);

  // 6) FFN: FF1 128x128 (512 blocks), FF2 128x64 (256 blocks)
  gemm_tile<1><<<512,256,0,stream>>>(hh, w1b, bw1, ff1, D_, DFF_, 16);
  gemm_n64<2><<<256,256,0,stream>>>(ff1, w2b, bw2, ffraw, DFF_, D_, 8);

  // 7) final double-LN
  final_kernel<<<M_,256,0,stream>>>(hf, ffraw, gf, bfv, g2, b2, out);
}